// Round 14
// baseline (421.549 us; speedup 1.0000x reference)
//
#include <hip/hip_runtime.h>
#include <hip/hip_bf16.h>

// ---------------------------------------------------------------------------
// LATTE heterogeneous GNN layer (gene/protein).
// R19: proj M-tile halved 128->64 (grid 3128 blocks, acc[4][2]=32 AGPR,
//      LDS 32KB) -> ~5 blocks/CU, ~20 waves/CU (was ~3/12, occ 26%).
//      R18 diagnosis: proj latency-bound with both pipes idle; R13 proved
//      fewer blocks hurt -> more blocks is the untested symmetric lever.
//      Same 8 K-iters, same per-element math (bit-identical). Attn tail
//      (R18's register/LDS fusion, verified -13us net) shrinks to the
//      64-row tile (16KB, aliases dead A-dbuf exactly). gather/CSR/cvt
//      unchanged.
// ---------------------------------------------------------------------------

typedef __attribute__((ext_vector_type(8))) short short8;   // 8 bf16
typedef __attribute__((ext_vector_type(4))) float floatx4;  // 4 f32 acc

__device__ __forceinline__ void gload16(const void* g, void* l) {
  __builtin_amdgcn_global_load_lds(
      (const __attribute__((address_space(1))) void*)g,
      (__attribute__((address_space(3))) void*)l, 16, 0, 0);
}

__device__ __forceinline__ ushort f2b(float x) {
  __hip_bfloat16 h = __float2bfloat16(x);
  return *reinterpret_cast<ushort*>(&h);
}
__device__ __forceinline__ float b2f_lo(unsigned v) { return __uint_as_float(v << 16); }
__device__ __forceinline__ float b2f_hi(unsigned v) { return __uint_as_float(v & 0xffff0000u); }

// ---------------- batched fp32 -> bf16 convert (weights only) --------------
struct CvtArgs {
  const float* src[8];
  ushort* dst[8];
  int valid[8];
  int total[8];
  int bstart[9];
};
__global__ __launch_bounds__(256) void cvt_multi(CvtArgs a) {
  int b = blockIdx.x;
  int e = 0;
#pragma unroll
  for (int j = 1; j < 8; ++j)
    if (b >= a.bstart[j]) e = j;
  int i = ((b - a.bstart[e]) * 256 + threadIdx.x) * 4;
  if (i >= a.total[e]) return;
  float4 v = make_float4(0.f, 0.f, 0.f, 0.f);
  if (i < a.valid[e]) v = *(const float4*)(a.src[e] + i);
  ushort4 o;
  o.x = f2b(v.x); o.y = f2b(v.y); o.z = f2b(v.z); o.w = f2b(v.w);
  *(ushort4*)(a.dst[e] + i) = o;
}

// ------------- fused l/r projection + in-register attn tanh-dot ------------
// 256 threads, grid (NPG/64, colHalf, type). 64-row M-tile: 4 waves each
// own 64x32 (acc[4][2]). A: fp32 x via global_load_lds, XOR-preswizzled
// source, fp32->bf16 at fragment read; B: bf16 W likewise; double-buffered,
// one barrier/iter. Epilogue: C-write also deposits the 64x128 bf16 tile
// into swizzled LDS (16KB, aliasing dead A-dbuf); one barrier; attn entry
// e=ty*2+colHalf runs from LDS(A) x global(aW) -> tl3/tr3.
struct ProjArgs {
  const float* x[2];
  const ushort* Wb[2];
  const float* bl[2];
  const float* br[2];
  ushort* lb[2];
  ushort* rb[2];
  int N[2];
  // fused attn entries, indexed e = ty*2 + colHalf
  const ushort* aW[4];
  const float* ab[4];
  const float* q0[4];   // cols 0..31
  const float* q1[4];   // cols 32..63 (BN=64 entries)
  float* o0[4];
  float* o1[4];
  int BN[4];
};
__global__ __launch_bounds__(256) void proj_lr_mfma(ProjArgs g) {
  const int ty = blockIdx.z;
  const float* xp = g.x[ty];
  const int N = g.N[ty];
  __shared__ float Asf[2 * 64 * 32];    // 2 x 8 KB fp32; attn tile aliases
  __shared__ ushort Bs[2 * 128 * 32];   // 2 x 8 KB bf16
  const int tid = threadIdx.x;
  const int lane = tid & 63;
  const int wv = tid >> 6;              // 0..3 -> N-strip of 32
  const int rowBase = blockIdx.x * 64;
  const int colHalf = blockIdx.y;
  const ushort* Wbase = g.Wb[ty] + (size_t)colHalf * 128 * 256;

  floatx4 acc[4][2] = {};

  auto stage = [&](int buf, int k0) {
    // A: 64 rows x 8 granules(16B fp32) = 512 granules, 2 issues/thread
#pragma unroll
    for (int i = 0; i < 2; ++i) {
      const int G = i * 256 + tid;                  // linear LDS granule
      const int row = G >> 3;                       // 0..63
      const int cg = (G & 7) ^ (row & 7);           // preswizzled src chunk
      const int xr = min(rowBase + row, N - 1);
      gload16(xp + (size_t)xr * 256 + k0 + cg * 4, &Asf[buf * 2048 + G * 4]);
    }
    // B: 128 rows x 4 granules(16B bf16) = 512 granules, 2 issues/thread
#pragma unroll
    for (int i = 0; i < 2; ++i) {
      const int G = i * 256 + tid;
      const int row = G >> 2;
      const int cg = (G & 3) ^ ((row >> 1) & 3);
      gload16(Wbase + (size_t)row * 256 + k0 + cg * 8, &Bs[buf * 4096 + G * 8]);
    }
  };

  stage(0, 0);
  __syncthreads();

  int t = 0;
  for (int k0 = 0; k0 < 256; k0 += 32) {
    if (k0 < 224) stage(t ^ 1, k0 + 32);
    const float* Ab = &Asf[t * 2048];
    const ushort* Bb = &Bs[t * 4096];
    short8 bf[2];
#pragma unroll
    for (int nt = 0; nt < 2; ++nt) {
      const int row = wv * 32 + nt * 16 + (lane & 15);   // output col 0..127
      const int c = (lane >> 4) ^ ((row >> 1) & 3);
      bf[nt] = *(const short8*)&Bb[(row * 4 + c) * 8];
    }
#pragma unroll
    for (int mt = 0; mt < 4; ++mt) {
      const int row = mt * 16 + (lane & 15);             // A row 0..63
      const int c0 = ((lane >> 4) * 2) ^ (row & 7);
      const int c1 = ((lane >> 4) * 2 + 1) ^ (row & 7);
      float4 f0 = *(const float4*)&Ab[(row * 8 + c0) * 4];
      float4 f1 = *(const float4*)&Ab[(row * 8 + c1) * 4];
      short8 a;
      a[0] = (short)f2b(f0.x); a[1] = (short)f2b(f0.y);
      a[2] = (short)f2b(f0.z); a[3] = (short)f2b(f0.w);
      a[4] = (short)f2b(f1.x); a[5] = (short)f2b(f1.y);
      a[6] = (short)f2b(f1.z); a[7] = (short)f2b(f1.w);
#pragma unroll
      for (int nt = 0; nt < 2; ++nt)
        acc[mt][nt] = __builtin_amdgcn_mfma_f32_16x16x32_bf16(a, bf[nt], acc[mt][nt], 0, 0, 0);
    }
    __syncthreads();
    t ^= 1;
  }

  // ---- C-write to global + swizzled LDS tile (same bf16 bytes) ----
  // All waves are past their final dbuf reads (loop-tail barrier), so
  // aliasing Asf as the 16KB 64x128 tile is safe without another barrier.
  ushort* tile = (ushort*)Asf;   // [row][swizzled chunk] 64x128 bf16
  const float* bias = colHalf ? g.br[ty] : g.bl[ty];
  ushort* outp = colHalf ? g.rb[ty] : g.lb[ty];
#pragma unroll
  for (int mt = 0; mt < 4; ++mt)
#pragma unroll
    for (int nt = 0; nt < 2; ++nt) {
      int col = wv * 32 + nt * 16 + (lane & 15);
      float bv = bias[col];
#pragma unroll
      for (int vi = 0; vi < 4; ++vi) {
        int row = mt * 16 + (lane >> 4) * 4 + vi;   // local 0..63
        ushort v = f2b(acc[mt][nt][vi] + bv);
        tile[row * 128 + (((col >> 3) ^ (row & 15)) << 3) + (col & 7)] = v;
        if (rowBase + row < N) outp[(size_t)(rowBase + row) * 128 + col] = v;
      }
    }
  __syncthreads();   // tile visible to all waves

  // ---- attn projection + tanh-dot from LDS tile x global aW ----
  const int e = ty * 2 + colHalf;
  const int NB = g.BN[e] >> 4;
  const ushort* aW = g.aW[e];
  floatx4 acc2[4] = {};
  for (int k0 = 0; k0 < 128; k0 += 32) {
    short8 bf2[4];
#pragma unroll
    for (int nt = 0; nt < 4; ++nt)
      if (nt < NB)
        bf2[nt] = *(const short8*)(aW + (size_t)(nt * 16 + (lane & 15)) * 128 +
                                   k0 + (lane >> 4) * 8);
    {
      const int row = wv * 16 + (lane & 15);        // 0..63
      const int c8 = (k0 >> 3) + (lane >> 4);       // chunk 0..15
      short8 a = *(const short8*)&tile[row * 128 + ((c8 ^ (row & 15)) << 3)];
#pragma unroll
      for (int nt = 0; nt < 4; ++nt)
        if (nt < NB)
          acc2[nt] = __builtin_amdgcn_mfma_f32_16x16x32_bf16(a, bf2[nt], acc2[nt], 0, 0, 0);
    }
  }

  const float* ab = g.ab[e];
  const int l15 = lane & 15;
  const bool two = (NB == 4);
  float bv2[4];
#pragma unroll
  for (int nt = 0; nt < 4; ++nt) bv2[nt] = (nt < NB) ? ab[nt * 16 + l15] : 0.f;
  float q0v0 = g.q0[e][l15], q0v1 = g.q0[e][16 + l15];
  float q1v0 = 0.f, q1v1 = 0.f;
  if (two) { q1v0 = g.q1[e][l15]; q1v1 = g.q1[e][16 + l15]; }
  float* o0 = g.o0[e];
  float* o1 = g.o1[e];
#pragma unroll
  for (int vi = 0; vi < 4; ++vi) {
    float slo = tanhf(acc2[0][vi] + bv2[0]) * q0v0
              + tanhf(acc2[1][vi] + bv2[1]) * q0v1;
    float shi = 0.f;
    if (two)
      shi = tanhf(acc2[2][vi] + bv2[2]) * q1v0
          + tanhf(acc2[3][vi] + bv2[3]) * q1v1;
#pragma unroll
    for (int m = 8; m >= 1; m >>= 1) {
      slo += __shfl_xor(slo, m, 64);   // xor<16 stays in the 16-lane group
      shi += __shfl_xor(shi, m, 64);
    }
    const int row = rowBase + wv * 16 + (lane >> 4) * 4 + vi;
    if (l15 == 0 && row < N) {
      o0[row] = slo;
      if (two) o1[row] = shi;
    }
  }
}

// ------- hist + rank: deg count and per-edge rank (coalesced) -------------
__global__ __launch_bounds__(256) void hist3_kernel(
    const int* __restrict__ e0, const int* __restrict__ e1,
    const int* __restrict__ e2, int* __restrict__ deg,
    int* __restrict__ rank, int E, int NG) {
  int e = blockIdx.x * 256 + threadIdx.x;
  if (e >= 3 * E) return;
  int mp = (e >= 2 * E) ? 2 : ((e >= E) ? 1 : 0);
  int el = e - mp * E;
  const int* ep = (mp == 0) ? e0 : (mp == 1) ? e1 : e2;
  int segb = (mp == 2) ? 2 * NG : mp * NG;
  rank[e] = atomicAdd(&deg[segb + ep[el]], 1);
}

// ------- hierarchical scan: A) tile scan, B) partials, C) add prefix ------
__global__ __launch_bounds__(256) void scanA_kernel(
    const int* __restrict__ deg, int* __restrict__ offsets,
    int* __restrict__ tile_tot, int n) {
  __shared__ int wtot[4];
  const int t = threadIdx.x;
  const int base = blockIdx.x * 2048 + t * 8;
  int v[8], pre[8], s = 0;
#pragma unroll
  for (int j = 0; j < 8; ++j) {
    v[j] = (base + j < n) ? deg[base + j] : 0;
    pre[j] = s;
    s += v[j];
  }
  const int lane = t & 63, wv = t >> 6;
  int x = s;
#pragma unroll
  for (int o = 1; o < 64; o <<= 1) {
    int u = __shfl_up(x, o, 64);
    if (lane >= o) x += u;
  }
  if (lane == 63) wtot[wv] = x;
  __syncthreads();
  int wpre = 0;
#pragma unroll
  for (int j = 0; j < 4; ++j) wpre += (j < wv) ? wtot[j] : 0;
  int excl = wpre + x - s;
#pragma unroll
  for (int j = 0; j < 8; ++j)
    if (base + j < n) offsets[base + j] = excl + pre[j];
  if (t == 255) tile_tot[blockIdx.x] = wpre + x;
}

__global__ __launch_bounds__(256) void scanB_kernel(
    const int* __restrict__ tile_tot, int* __restrict__ tile_pre,
    int* __restrict__ offsets, int T, int n) {
  __shared__ int wtot[4];
  const int t = threadIdx.x;
  int v = (t < T) ? tile_tot[t] : 0;
  const int lane = t & 63, wv = t >> 6;
  int x = v;
#pragma unroll
  for (int o = 1; o < 64; o <<= 1) {
    int u = __shfl_up(x, o, 64);
    if (lane >= o) x += u;
  }
  if (lane == 63) wtot[wv] = x;
  __syncthreads();
  int wpre = 0;
#pragma unroll
  for (int j = 0; j < 4; ++j) wpre += (j < wv) ? wtot[j] : 0;
  if (t < T) tile_pre[t] = wpre + x - v;
  if (t == 255) offsets[n] = wpre + x;  // grand total
}

__global__ __launch_bounds__(256) void scanC_kernel(
    int* __restrict__ offsets, const int* __restrict__ tile_pre, int n) {
  const int add = tile_pre[blockIdx.x];
  const int base = blockIdx.x * 2048 + threadIdx.x * 8;
#pragma unroll
  for (int j = 0; j < 8; ++j)
    if (base + j < n) offsets[base + j] += add;
}

// ------- scatter3: pos = offsets[node] + rank[e]; writes {d*256, w} -------
__global__ __launch_bounds__(256) void scatter3_kernel(
    const int* __restrict__ e0, const int* __restrict__ e1,
    const int* __restrict__ e2, const int* __restrict__ rank,
    const int* __restrict__ offsets,
    const float* __restrict__ tl3, const float* __restrict__ tr3,
    const float* __restrict__ sharp, int2* __restrict__ recs,
    int E, int NG, int NP) {
  int e = blockIdx.x * 256 + threadIdx.x;
  if (e >= 3 * E) return;
  int mp = (e >= 2 * E) ? 2 : ((e >= E) ? 1 : 0);
  int el = e - mp * E;
  const int* ep = (mp == 0) ? e0 : (mp == 1) ? e1 : e2;
  int s = ep[el], d = ep[el + E];
  int hb = (mp == 2) ? 2 * NG : mp * NG;                 // head/offsets base
  int tb = (mp == 0) ? 0 : (mp == 1) ? NG : NG + NP;     // tr3 segment base
  // |tl+tr| <= sum|qw| ~ 10 -> exp safe in fp32 without max-shift.
  float w = expf((tl3[hb + s] + tr3[tb + d]) * sharp[mp]);
  recs[offsets[hb + s] + rank[e]] = make_int2(d << 8, __float_as_int(w));
}

// ------- fused gather + relation combine: QUARTER per OUTPUT node ---------
__global__ __launch_bounds__(256) void gather_combine(
    const ushort* __restrict__ rb_gene, const ushort* __restrict__ rb_prot,
    const ushort* __restrict__ lb_gene, const ushort* __restrict__ lb_prot,
    const int* __restrict__ offsets, const int2* __restrict__ recs,
    const float* __restrict__ cgW, const float* __restrict__ cgb,
    const float* __restrict__ cpW, const float* __restrict__ cpb,
    float* __restrict__ out_gene, float* __restrict__ out_prot,
    int NG, int NP) {
  const int lane = threadIdx.x & 63;
  const int l16 = lane & 15;
  const int node = blockIdx.x * 16 + (threadIdx.x >> 4);
  if (node >= NG + NP) return;
  const bool isGene = node < NG;
  const unsigned coloff = (unsigned)l16 << 4;   // 16 B per lane
  const unsigned OMASK = 0x00FFFF00u;           // bounds stray row offsets

  const int h0 = isGene ? node : NG + node;     // gg for genes / pp for prots
  const int j0a = offsets[h0];
  const int ca = offsets[h0 + 1] - j0a;
  int j0b = 0, cb2 = 0;
  if (isGene) {
    j0b = offsets[NG + node];
    cb2 = offsets[NG + node + 1] - j0b;
  }

  float a0[8] = {0.f, 0.f, 0.f, 0.f, 0.f, 0.f, 0.f, 0.f};
  float a1[8] = {0.f, 0.f, 0.f, 0.f, 0.f, 0.f, 0.f, 0.f};
  float ds0 = 0.f, ds1 = 0.f;
  const ushort* rtA = isGene ? rb_gene : rb_prot;

  if (isGene) {
    const int cmax = (ca > cb2) ? ca : cb2;
    if (cmax > 0) {
      int2 rA[4], rB[4];
#pragma unroll
      for (int p = 0; p < 4; ++p) {
        rA[p] = recs[j0a + ((p < ca) ? p : 0)];
        rB[p] = recs[j0b + ((p < cb2) ? p : 0)];
      }
      const int nit = (cmax + 3) >> 2;
      for (int it = 0; it < nit; ++it) {
        const int b = it * 4;
        float wA[4], wB[4];
        uint4 vA[4], vB[4];
#pragma unroll
        for (int p = 0; p < 4; ++p) {
          wA[p] = (b + p < ca)  ? __int_as_float(rA[p].y) : 0.f;
          wB[p] = (b + p < cb2) ? __int_as_float(rB[p].y) : 0.f;
          vA[p] = *(const uint4*)((const char*)rtA + (((unsigned)rA[p].x & OMASK) + coloff));
          vB[p] = *(const uint4*)((const char*)rb_prot + (((unsigned)rB[p].x & OMASK) + coloff));
        }
        const int nb = b + 4;
#pragma unroll
        for (int p = 0; p < 4; ++p) {
          rA[p] = recs[j0a + ((nb + p < ca) ? nb + p : 0)];
          rB[p] = recs[j0b + ((nb + p < cb2) ? nb + p : 0)];
        }
#pragma unroll
        for (int p = 0; p < 4; ++p) {
          ds0 += wA[p];
          a0[0] += b2f_lo(vA[p].x) * wA[p]; a0[1] += b2f_hi(vA[p].x) * wA[p];
          a0[2] += b2f_lo(vA[p].y) * wA[p]; a0[3] += b2f_hi(vA[p].y) * wA[p];
          a0[4] += b2f_lo(vA[p].z) * wA[p]; a0[5] += b2f_hi(vA[p].z) * wA[p];
          a0[6] += b2f_lo(vA[p].w) * wA[p]; a0[7] += b2f_hi(vA[p].w) * wA[p];
          ds1 += wB[p];
          a1[0] += b2f_lo(vB[p].x) * wB[p]; a1[1] += b2f_hi(vB[p].x) * wB[p];
          a1[2] += b2f_lo(vB[p].y) * wB[p]; a1[3] += b2f_hi(vB[p].y) * wB[p];
          a1[4] += b2f_lo(vB[p].z) * wB[p]; a1[5] += b2f_hi(vB[p].z) * wB[p];
          a1[6] += b2f_lo(vB[p].w) * wB[p]; a1[7] += b2f_hi(vB[p].w) * wB[p];
        }
      }
    }
  } else {
    if (ca > 0) {
      int2 r0 = recs[j0a];
      int2 r1 = recs[j0a + ((1 < ca) ? 1 : 0)];
      int2 r2 = recs[j0a + ((2 < ca) ? 2 : 0)];
      int2 r3 = recs[j0a + ((3 < ca) ? 3 : 0)];
      const int nit = (ca + 3) >> 2;
      for (int it = 0; it < nit; ++it) {
        const int b = it * 4;
        const float w0 = (b < ca)     ? __int_as_float(r0.y) : 0.f;
        const float w1 = (b + 1 < ca) ? __int_as_float(r1.y) : 0.f;
        const float w2 = (b + 2 < ca) ? __int_as_float(r2.y) : 0.f;
        const float w3 = (b + 3 < ca) ? __int_as_float(r3.y) : 0.f;
        const uint4 v0 = *(const uint4*)((const char*)rtA + (((unsigned)r0.x & OMASK) + coloff));
        const uint4 v1 = *(const uint4*)((const char*)rtA + (((unsigned)r1.x & OMASK) + coloff));
        const uint4 v2 = *(const uint4*)((const char*)rtA + (((unsigned)r2.x & OMASK) + coloff));
        const uint4 v3 = *(const uint4*)((const char*)rtA + (((unsigned)r3.x & OMASK) + coloff));
        const int nb = b + 4;
        r0 = recs[j0a + ((nb < ca) ? nb : 0)];
        r1 = recs[j0a + ((nb + 1 < ca) ? nb + 1 : 0)];
        r2 = recs[j0a + ((nb + 2 < ca) ? nb + 2 : 0)];
        r3 = recs[j0a + ((nb + 3 < ca) ? nb + 3 : 0)];
        ds0 += (w0 + w1) + (w2 + w3);
        a0[0] += b2f_lo(v0.x) * w0 + b2f_lo(v1.x) * w1 + b2f_lo(v2.x) * w2 + b2f_lo(v3.x) * w3;
        a0[1] += b2f_hi(v0.x) * w0 + b2f_hi(v1.x) * w1 + b2f_hi(v2.x) * w2 + b2f_hi(v3.x) * w3;
        a0[2] += b2f_lo(v0.y) * w0 + b2f_lo(v1.y) * w1 + b2f_lo(v2.y) * w2 + b2f_lo(v3.y) * w3;
        a0[3] += b2f_hi(v0.y) * w0 + b2f_hi(v1.y) * w1 + b2f_hi(v2.y) * w2 + b2f_hi(v3.y) * w3;
        a0[4] += b2f_lo(v0.z) * w0 + b2f_lo(v1.z) * w1 + b2f_lo(v2.z) * w2 + b2f_lo(v3.z) * w3;
        a0[5] += b2f_hi(v0.z) * w0 + b2f_hi(v1.z) * w1 + b2f_hi(v2.z) * w2 + b2f_hi(v3.z) * w3;
        a0[6] += b2f_lo(v0.w) * w0 + b2f_lo(v1.w) * w1 + b2f_lo(v2.w) * w2 + b2f_lo(v3.w) * w3;
        a0[7] += b2f_hi(v0.w) * w0 + b2f_hi(v1.w) * w1 + b2f_hi(v2.w) * w2 + b2f_hi(v3.w) * w3;
      }
    }
  }

  // ---- epilogue (per quarter; ds is lane-uniform within the quarter) ----
  const float inv0 = 1.f / (ds0 + 1e-16f);
  const float inv1 = 1.f / (ds1 + 1e-16f);
  float g0[8], g1[8], self[8];
#pragma unroll
  for (int c = 0; c < 8; ++c) { g0[c] = a0[c] * inv0; g1[c] = a1[c] * inv1; }
  {
    const ushort* lbp = isGene ? lb_gene + (size_t)node * 128
                               : lb_prot + (size_t)(node - NG) * 128;
    uint4 sv = *(const uint4*)(lbp + l16 * 8);
    self[0] = b2f_lo(sv.x); self[1] = b2f_hi(sv.x);
    self[2] = b2f_lo(sv.y); self[3] = b2f_hi(sv.y);
    self[4] = b2f_lo(sv.z); self[5] = b2f_hi(sv.z);
    self[6] = b2f_lo(sv.w); self[7] = b2f_hi(sv.w);
  }

  const float* cW = isGene ? cgW : cpW;
  const float cb = isGene ? cgb[0] : cpb[0];
  const float4 wlo = *(const float4*)(cW + l16 * 8);
  const float4 whi = *(const float4*)(cW + l16 * 8 + 4);
  float p0 = g0[0] * wlo.x + g0[1] * wlo.y + g0[2] * wlo.z + g0[3] * wlo.w +
             g0[4] * whi.x + g0[5] * whi.y + g0[6] * whi.z + g0[7] * whi.w;
  float p1 = g1[0] * wlo.x + g1[1] * wlo.y + g1[2] * wlo.z + g1[3] * wlo.w +
             g1[4] * whi.x + g1[5] * whi.y + g1[6] * whi.z + g1[7] * whi.w;
  float ps = self[0] * wlo.x + self[1] * wlo.y + self[2] * wlo.z + self[3] * wlo.w +
             self[4] * whi.x + self[5] * whi.y + self[6] * whi.z + self[7] * whi.w;
#pragma unroll
  for (int m = 8; m >= 1; m >>= 1) {  // reduce the quarter's 16 col-lanes
    p0 += __shfl_xor(p0, m, 64);
    p1 += __shfl_xor(p1, m, 64);
    ps += __shfl_xor(ps, m, 64);
  }
  const float s0 = p0 + cb, s1 = p1 + cb, ss = ps + cb;
  const float mx = isGene ? fmaxf(fmaxf(s0, s1), ss) : fmaxf(s0, ss);
  const float e0 = expf(s0 - mx);
  const float e1 = isGene ? expf(s1 - mx) : 0.f;
  const float es = expf(ss - mx);
  const float sum = e0 + e1 + es;
  const float b0 = e0 / sum, b1 = e1 / sum, bs = es / sum;

  float4 o0, o1;
  o0.x = fmaxf(g0[0] * b0 + g1[0] * b1 + self[0] * bs, 0.f);
  o0.y = fmaxf(g0[1] * b0 + g1[1] * b1 + self[1] * bs, 0.f);
  o0.z = fmaxf(g0[2] * b0 + g1[2] * b1 + self[2] * bs, 0.f);
  o0.w = fmaxf(g0[3] * b0 + g1[3] * b1 + self[3] * bs, 0.f);
  o1.x = fmaxf(g0[4] * b0 + g1[4] * b1 + self[4] * bs, 0.f);
  o1.y = fmaxf(g0[5] * b0 + g1[5] * b1 + self[5] * bs, 0.f);
  o1.z = fmaxf(g0[6] * b0 + g1[6] * b1 + self[6] * bs, 0.f);
  o1.w = fmaxf(g0[7] * b0 + g1[7] * b1 + self[7] * bs, 0.f);
  float* op = isGene ? out_gene + (size_t)node * 128
                     : out_prot + (size_t)(node - NG) * 128;
  *(float4*)(op + l16 * 8) = o0;
  *(float4*)(op + l16 * 8 + 4) = o1;
}

// ---------------------------------------------------------------------------
extern "C" void kernel_launch(void* const* d_in, const int* in_sizes, int n_in,
                              void* d_out, int out_size, void* d_ws,
                              size_t ws_size, hipStream_t stream) {
  const float* x_gene  = (const float*)d_in[0];
  const float* x_prot  = (const float*)d_in[1];
  const float* Wl_gene = (const float*)d_in[2];
  const float* bl_gene = (const float*)d_in[3];
  const float* Wr_gene = (const float*)d_in[4];
  const float* br_gene = (const float*)d_in[5];
  const float* Wl_prot = (const float*)d_in[6];
  const float* bl_prot = (const float*)d_in[7];
  const float* Wr_prot = (const float*)d_in[8];
  const float* br_prot = (const float*)d_in[9];
  const float* alW     = (const float*)d_in[10];  // [3,32,128] contiguous
  const float* alb     = (const float*)d_in[11];  // [3,32] contiguous
  const float* arW     = (const float*)d_in[12];
  const float* arb     = (const float*)d_in[13];
  const float* qw      = (const float*)d_in[14];  // [3,64,1]
  const float* sharp   = (const float*)d_in[15];
  const float* cgW     = (const float*)d_in[16];
  const float* cgb     = (const float*)d_in[17];
  const float* cpW     = (const float*)d_in[18];
  const float* cpb     = (const float*)d_in[19];
  const int* e_gg      = (const int*)d_in[20];
  const int* e_gp      = (const int*)d_in[21];
  const int* e_pp      = (const int*)d_in[22];

  const int NG = in_sizes[0] / 256;
  const int NP = in_sizes[1] / 256;
  const int E  = in_sizes[20] / 2;
  const int NPG = (NG + 127) & ~127;
  const int NT = 2 * NG + NP;          // concatenated head-node space
  const int NR = NG + 2 * NP;          // concatenated tail-node space (tr)

  char* base = (char*)d_ws;
  size_t off = 0;
  auto alloc = [&](size_t bytes) {
    void* p = base + off;
    off = (off + bytes + 255) & ~(size_t)255;
    return p;
  };
  ushort* Wlr_gene = (ushort*)alloc(256 * 256 * 2);
  ushort* Wlr_prot = (ushort*)alloc(256 * 256 * 2);
  ushort* alWb     = (ushort*)alloc(96 * 128 * 2);
  ushort* arWb     = (ushort*)alloc(96 * 128 * 2);
  ushort* lb_gene  = (ushort*)alloc((size_t)NPG * 128 * 2);
  ushort* rb_gene  = (ushort*)alloc((size_t)NPG * 128 * 2);
  ushort* lb_prot  = (ushort*)alloc((size_t)NPG * 128 * 2);
  ushort* rb_prot  = (ushort*)alloc((size_t)NPG * 128 * 2);
  int*    deg      = (int*)alloc((size_t)NT * 4);
  int*    offsets  = (int*)alloc((size_t)(NT + 1) * 4);
  const int TILES  = (NT + 2047) / 2048;
  int*    tile_tot = (int*)alloc((size_t)TILES * 4);
  int*    tile_pre = (int*)alloc((size_t)TILES * 4);
  int*    rank     = (int*)alloc((size_t)(3 * E) * 4);
  int2*   recs     = (int2*)alloc((size_t)(3 * E) * sizeof(int2));
  float*  tl3      = (float*)alloc((size_t)NT * 4);
  float*  tr3      = (float*)alloc((size_t)NR * 4);

  float* out_gene = (float*)d_out;
  float* out_prot = out_gene + (size_t)NG * 128;

  dim3 blk(256);

  // ---- 0) bf16 conversions, weights only (1 tiny dispatch) ----
  {
    CvtArgs a;
    const float* srcs[8] = {Wl_gene, Wr_gene, Wl_prot, Wr_prot, alW, arW,
                            Wl_gene, Wl_gene};
    ushort* dsts[8] = {Wlr_gene, Wlr_gene + 128 * 256,
                       Wlr_prot, Wlr_prot + 128 * 256, alWb, arWb,
                       Wlr_gene, Wlr_gene};
    int sizes[8] = {128 * 256, 128 * 256, 128 * 256, 128 * 256,
                    96 * 128, 96 * 128, 0, 0};
    int b = 0;
    for (int j = 0; j < 8; ++j) {
      a.src[j] = srcs[j]; a.dst[j] = dsts[j];
      a.valid[j] = sizes[j]; a.total[j] = sizes[j];
      a.bstart[j] = b;
      b += (sizes[j] / 4 + 255) / 256;
    }
    a.bstart[8] = b;
    cvt_multi<<<b, blk, 0, stream>>>(a);
  }

  // ---- 1) fused l/r projections + in-register attn tanh-dot (1 dispatch) --
  {
    ProjArgs p;
    p.x[0] = x_gene; p.x[1] = x_prot;
    p.Wb[0] = Wlr_gene; p.Wb[1] = Wlr_prot;
    p.bl[0] = bl_gene; p.bl[1] = bl_prot;
    p.br[0] = br_gene; p.br[1] = br_prot;
    p.lb[0] = lb_gene; p.lb[1] = lb_prot;
    p.rb[0] = rb_gene; p.rb[1] = rb_prot;
    p.N[0] = NG; p.N[1] = NP;
    // attn entries: e = ty*2 + colHalf
    p.aW[0] = alWb;            p.ab[0] = alb;      p.BN[0] = 64;
    p.q0[0] = qw + 0;  p.q1[0] = qw + 64;  p.o0[0] = tl3;          p.o1[0] = tl3 + NG;
    p.aW[1] = arWb;            p.ab[1] = arb;      p.BN[1] = 32;
    p.q0[1] = qw + 32; p.q1[1] = qw + 32;  p.o0[1] = tr3;          p.o1[1] = tr3;
    p.aW[2] = alWb + 64 * 128; p.ab[2] = alb + 64; p.BN[2] = 32;
    p.q0[2] = qw + 128; p.q1[2] = qw + 128; p.o0[2] = tl3 + 2 * NG; p.o1[2] = tl3 + 2 * NG;
    p.aW[3] = arWb + 32 * 128; p.ab[3] = arb + 32; p.BN[3] = 64;
    p.q0[3] = qw + 96; p.q1[3] = qw + 160; p.o0[3] = tr3 + NG;     p.o1[3] = tr3 + NG + NP;
    proj_lr_mfma<<<dim3(NPG / 64, 2, 2), blk, 0, stream>>>(p);
  }

  // ---- 2) CSR build (hist+rank -> scan -> scatter{d*256,w}) ----
  const int gridE3 = (3 * E + 255) / 256;
  hipMemsetAsync(deg, 0, (size_t)NT * sizeof(int), stream);
  hist3_kernel<<<gridE3, blk, 0, stream>>>(e_gg, e_gp, e_pp, deg, rank, E, NG);
  scanA_kernel<<<TILES, blk, 0, stream>>>(deg, offsets, tile_tot, NT);
  scanB_kernel<<<1, blk, 0, stream>>>(tile_tot, tile_pre, offsets, TILES, NT);
  scanC_kernel<<<TILES, blk, 0, stream>>>(offsets, tile_pre, NT);
  scatter3_kernel<<<gridE3, blk, 0, stream>>>(e_gg, e_gp, e_pp, rank, offsets,
                                              tl3, tr3, sharp, recs, E, NG, NP);

  // ---- 3) fused gather + relation combine (1 dispatch) ----
  gather_combine<<<(NG + NP + 15) / 16, blk, 0, stream>>>(
      rb_gene, rb_prot, lb_gene, lb_prot, offsets, recs,
      cgW, cgb, cpW, cpb, out_gene, out_prot, NG, NP);
}

// Round 15
// 384.719 us; speedup vs baseline: 1.0957x; 1.0957x over previous
//
#include <hip/hip_runtime.h>
#include <hip/hip_bf16.h>

// ---------------------------------------------------------------------------
// LATTE heterogeneous GNN layer (gene/protein).
// R20: REVERT proj to R18's verified 128-tile shape (R19's 64-tile raised
//      proj to 106us: occupancy is VGPR-capped at 76 regs, not LDS, so
//      smaller tiles only doubled overhead). NEW: hist3 is FUSED into the
//      proj dispatch as trailing blocks (flat grid: first 1564 = proj,
//      next 5860 = edge histogram). hist3 depends only on edge lists;
//      proj is 93% idle (MfmaUtil 7%) -> hist blocks co-schedule into
//      proj's idle issue slots nearly free, deleting one of the two
//      suspected ~40-80us hidden dispatches. memset(deg) moved first.
//      gather/scans/scatter3/cvt byte-identical to R18 (398us verified).
// ---------------------------------------------------------------------------

typedef __attribute__((ext_vector_type(8))) short short8;   // 8 bf16
typedef __attribute__((ext_vector_type(4))) float floatx4;  // 4 f32 acc

__device__ __forceinline__ void gload16(const void* g, void* l) {
  __builtin_amdgcn_global_load_lds(
      (const __attribute__((address_space(1))) void*)g,
      (__attribute__((address_space(3))) void*)l, 16, 0, 0);
}

__device__ __forceinline__ ushort f2b(float x) {
  __hip_bfloat16 h = __float2bfloat16(x);
  return *reinterpret_cast<ushort*>(&h);
}
__device__ __forceinline__ float b2f_lo(unsigned v) { return __uint_as_float(v << 16); }
__device__ __forceinline__ float b2f_hi(unsigned v) { return __uint_as_float(v & 0xffff0000u); }

// ---------------- batched fp32 -> bf16 convert (weights only) --------------
struct CvtArgs {
  const float* src[8];
  ushort* dst[8];
  int valid[8];
  int total[8];
  int bstart[9];
};
__global__ __launch_bounds__(256) void cvt_multi(CvtArgs a) {
  int b = blockIdx.x;
  int e = 0;
#pragma unroll
  for (int j = 1; j < 8; ++j)
    if (b >= a.bstart[j]) e = j;
  int i = ((b - a.bstart[e]) * 256 + threadIdx.x) * 4;
  if (i >= a.total[e]) return;
  float4 v = make_float4(0.f, 0.f, 0.f, 0.f);
  if (i < a.valid[e]) v = *(const float4*)(a.src[e] + i);
  ushort4 o;
  o.x = f2b(v.x); o.y = f2b(v.y); o.z = f2b(v.z); o.w = f2b(v.w);
  *(ushort4*)(a.dst[e] + i) = o;
}

// ------------- fused l/r projection + attn tanh-dot + edge histogram ------
// Flat 1D grid: blocks [0, projBlocks) do the R18 proj+attn; blocks
// [projBlocks, projBlocks+histBlocks) do hist3's edge histogram (deg
// atomicAdd + rank). Hist blocks branch uniformly and never reach a
// barrier. Proj decode: ty = bid&1, colHalf = (bid>>1)&1, rowTile = bid>>2.
struct ProjArgs {
  const float* x[2];
  const ushort* Wb[2];
  const float* bl[2];
  const float* br[2];
  ushort* lb[2];
  ushort* rb[2];
  int N[2];
  // fused attn entries, indexed e = ty*2 + colHalf
  const ushort* aW[4];
  const float* ab[4];
  const float* q0[4];   // cols 0..31
  const float* q1[4];   // cols 32..63 (BN=64 entries)
  float* o0[4];
  float* o1[4];
  int BN[4];
  // fused hist3
  const int* e0;
  const int* e1;
  const int* e2;
  int* deg;
  int* rank;
  int E;
  int NGh;
  int projBlocks;
};
__global__ __launch_bounds__(256) void proj_lr_mfma(ProjArgs g) {
  __shared__ float Asf[2 * 128 * 32];   // 2 x 16 KB fp32; attn tile aliases
  __shared__ ushort Bs[2 * 128 * 32];   // 2 x 8 KB bf16
  const int tid = threadIdx.x;

  // ---- fused hist3 path (uniform branch; no barriers touched) ----
  if ((int)blockIdx.x >= g.projBlocks) {
    const int E = g.E;
    int e = ((int)blockIdx.x - g.projBlocks) * 256 + tid;
    if (e < 3 * E) {
      int mp = (e >= 2 * E) ? 2 : ((e >= E) ? 1 : 0);
      int el = e - mp * E;
      const int* ep = (mp == 0) ? g.e0 : (mp == 1) ? g.e1 : g.e2;
      int segb = (mp == 2) ? 2 * g.NGh : mp * g.NGh;
      g.rank[e] = atomicAdd(&g.deg[segb + ep[el]], 1);
    }
    return;
  }

  const int pb = blockIdx.x;
  const int ty = pb & 1;
  const int colHalf = (pb >> 1) & 1;
  const float* xp = g.x[ty];
  const int N = g.N[ty];
  const int lane = tid & 63;
  const int wv = tid >> 6;
  const int wm = wv & 1, wn = wv >> 1;
  const int rowBase = (pb >> 2) * 128;
  const ushort* Wbase = g.Wb[ty] + (size_t)colHalf * 128 * 256;

  floatx4 acc[4][4] = {};

  auto stage = [&](int buf, int k0) {
#pragma unroll
    for (int i = 0; i < 4; ++i) {
      const int G = i * 256 + wv * 64 + lane;       // linear LDS granule
      const int row = G >> 3;
      const int cg = (G & 7) ^ (row & 7);           // preswizzled src chunk
      const int xr = min(rowBase + row, N - 1);
      gload16(xp + (size_t)xr * 256 + k0 + cg * 4, &Asf[buf * 4096 + G * 4]);
    }
#pragma unroll
    for (int i = 0; i < 2; ++i) {
      const int G = i * 256 + wv * 64 + lane;
      const int row = G >> 2;
      const int cg = (G & 3) ^ ((row >> 1) & 3);
      gload16(Wbase + (size_t)row * 256 + k0 + cg * 8, &Bs[buf * 4096 + G * 8]);
    }
  };

  stage(0, 0);
  __syncthreads();

  int t = 0;
  for (int k0 = 0; k0 < 256; k0 += 32) {
    if (k0 < 224) stage(t ^ 1, k0 + 32);
    const float* Ab = &Asf[t * 4096];
    const ushort* Bb = &Bs[t * 4096];
    short8 bf[4];
#pragma unroll
    for (int nt = 0; nt < 4; ++nt) {
      const int row = wn * 64 + nt * 16 + (lane & 15);
      const int c = (lane >> 4) ^ ((row >> 1) & 3);
      bf[nt] = *(const short8*)&Bb[(row * 4 + c) * 8];
    }
#pragma unroll
    for (int mt = 0; mt < 4; ++mt) {
      const int row = wm * 64 + mt * 16 + (lane & 15);
      const int c0 = ((lane >> 4) * 2) ^ (row & 7);
      const int c1 = ((lane >> 4) * 2 + 1) ^ (row & 7);
      float4 f0 = *(const float4*)&Ab[(row * 8 + c0) * 4];
      float4 f1 = *(const float4*)&Ab[(row * 8 + c1) * 4];
      short8 a;
      a[0] = (short)f2b(f0.x); a[1] = (short)f2b(f0.y);
      a[2] = (short)f2b(f0.z); a[3] = (short)f2b(f0.w);
      a[4] = (short)f2b(f1.x); a[5] = (short)f2b(f1.y);
      a[6] = (short)f2b(f1.z); a[7] = (short)f2b(f1.w);
#pragma unroll
      for (int nt = 0; nt < 4; ++nt)
        acc[mt][nt] = __builtin_amdgcn_mfma_f32_16x16x32_bf16(a, bf[nt], acc[mt][nt], 0, 0, 0);
    }
    __syncthreads();
    t ^= 1;
  }

  // ---- C-write to global + swizzled LDS tile (same bf16 bytes) ----
  ushort* tile = (ushort*)Asf;   // [row][swizzled chunk] 128x128 bf16
  const float* bias = colHalf ? g.br[ty] : g.bl[ty];
  ushort* outp = colHalf ? g.rb[ty] : g.lb[ty];
#pragma unroll
  for (int mt = 0; mt < 4; ++mt)
#pragma unroll
    for (int nt = 0; nt < 4; ++nt) {
      int col = wn * 64 + nt * 16 + (lane & 15);
      float bv = bias[col];
#pragma unroll
      for (int vi = 0; vi < 4; ++vi) {
        int row = wm * 64 + mt * 16 + (lane >> 4) * 4 + vi;   // local 0..127
        ushort v = f2b(acc[mt][nt][vi] + bv);
        tile[row * 128 + (((col >> 3) ^ (row & 15)) << 3) + (col & 7)] = v;
        if (rowBase + row < N) outp[(size_t)(rowBase + row) * 128 + col] = v;
      }
    }
  __syncthreads();   // tile visible to all waves

  // ---- attn projection + tanh-dot from LDS tile x global aW ----
  const int e = ty * 2 + colHalf;
  const int NB = g.BN[e] >> 4;
  const ushort* aW = g.aW[e];
  floatx4 acc2[2][4] = {};
  for (int k0 = 0; k0 < 128; k0 += 32) {
    short8 bf2[4];
#pragma unroll
    for (int nt = 0; nt < 4; ++nt)
      if (nt < NB)
        bf2[nt] = *(const short8*)(aW + (size_t)(nt * 16 + (lane & 15)) * 128 +
                                   k0 + (lane >> 4) * 8);
#pragma unroll
    for (int mt = 0; mt < 2; ++mt) {
      const int row = wv * 32 + mt * 16 + (lane & 15);
      const int c8 = (k0 >> 3) + (lane >> 4);          // chunk 0..15
      short8 a = *(const short8*)&tile[row * 128 + ((c8 ^ (row & 15)) << 3)];
#pragma unroll
      for (int nt = 0; nt < 4; ++nt)
        if (nt < NB)
          acc2[mt][nt] = __builtin_amdgcn_mfma_f32_16x16x32_bf16(a, bf2[nt], acc2[mt][nt], 0, 0, 0);
    }
  }

  const float* ab = g.ab[e];
  const int l15 = lane & 15;
  const bool two = (NB == 4);
  float bv2[4];
#pragma unroll
  for (int nt = 0; nt < 4; ++nt) bv2[nt] = (nt < NB) ? ab[nt * 16 + l15] : 0.f;
  float q0v0 = g.q0[e][l15], q0v1 = g.q0[e][16 + l15];
  float q1v0 = 0.f, q1v1 = 0.f;
  if (two) { q1v0 = g.q1[e][l15]; q1v1 = g.q1[e][16 + l15]; }
  float* o0 = g.o0[e];
  float* o1 = g.o1[e];
#pragma unroll
  for (int mt = 0; mt < 2; ++mt)
#pragma unroll
    for (int vi = 0; vi < 4; ++vi) {
      float slo = tanhf(acc2[mt][0][vi] + bv2[0]) * q0v0
                + tanhf(acc2[mt][1][vi] + bv2[1]) * q0v1;
      float shi = 0.f;
      if (two)
        shi = tanhf(acc2[mt][2][vi] + bv2[2]) * q1v0
            + tanhf(acc2[mt][3][vi] + bv2[3]) * q1v1;
#pragma unroll
      for (int m = 8; m >= 1; m >>= 1) {
        slo += __shfl_xor(slo, m, 64);   // xor<16 stays in the 16-lane group
        shi += __shfl_xor(shi, m, 64);
      }
      const int row = rowBase + wv * 32 + mt * 16 + (lane >> 4) * 4 + vi;
      if (l15 == 0 && row < N) {
        o0[row] = slo;
        if (two) o1[row] = shi;
      }
    }
}

// ------- hierarchical scan: A) tile scan, B) partials, C) add prefix ------
__global__ __launch_bounds__(256) void scanA_kernel(
    const int* __restrict__ deg, int* __restrict__ offsets,
    int* __restrict__ tile_tot, int n) {
  __shared__ int wtot[4];
  const int t = threadIdx.x;
  const int base = blockIdx.x * 2048 + t * 8;
  int v[8], pre[8], s = 0;
#pragma unroll
  for (int j = 0; j < 8; ++j) {
    v[j] = (base + j < n) ? deg[base + j] : 0;
    pre[j] = s;
    s += v[j];
  }
  const int lane = t & 63, wv = t >> 6;
  int x = s;
#pragma unroll
  for (int o = 1; o < 64; o <<= 1) {
    int u = __shfl_up(x, o, 64);
    if (lane >= o) x += u;
  }
  if (lane == 63) wtot[wv] = x;
  __syncthreads();
  int wpre = 0;
#pragma unroll
  for (int j = 0; j < 4; ++j) wpre += (j < wv) ? wtot[j] : 0;
  int excl = wpre + x - s;
#pragma unroll
  for (int j = 0; j < 8; ++j)
    if (base + j < n) offsets[base + j] = excl + pre[j];
  if (t == 255) tile_tot[blockIdx.x] = wpre + x;
}

__global__ __launch_bounds__(256) void scanB_kernel(
    const int* __restrict__ tile_tot, int* __restrict__ tile_pre,
    int* __restrict__ offsets, int T, int n) {
  __shared__ int wtot[4];
  const int t = threadIdx.x;
  int v = (t < T) ? tile_tot[t] : 0;
  const int lane = t & 63, wv = t >> 6;
  int x = v;
#pragma unroll
  for (int o = 1; o < 64; o <<= 1) {
    int u = __shfl_up(x, o, 64);
    if (lane >= o) x += u;
  }
  if (lane == 63) wtot[wv] = x;
  __syncthreads();
  int wpre = 0;
#pragma unroll
  for (int j = 0; j < 4; ++j) wpre += (j < wv) ? wtot[j] : 0;
  if (t < T) tile_pre[t] = wpre + x - v;
  if (t == 255) offsets[n] = wpre + x;  // grand total
}

__global__ __launch_bounds__(256) void scanC_kernel(
    int* __restrict__ offsets, const int* __restrict__ tile_pre, int n) {
  const int add = tile_pre[blockIdx.x];
  const int base = blockIdx.x * 2048 + threadIdx.x * 8;
#pragma unroll
  for (int j = 0; j < 8; ++j)
    if (base + j < n) offsets[base + j] += add;
}

// ------- scatter3: pos = offsets[node] + rank[e]; writes {d*256, w} -------
__global__ __launch_bounds__(256) void scatter3_kernel(
    const int* __restrict__ e0, const int* __restrict__ e1,
    const int* __restrict__ e2, const int* __restrict__ rank,
    const int* __restrict__ offsets,
    const float* __restrict__ tl3, const float* __restrict__ tr3,
    const float* __restrict__ sharp, int2* __restrict__ recs,
    int E, int NG, int NP) {
  int e = blockIdx.x * 256 + threadIdx.x;
  if (e >= 3 * E) return;
  int mp = (e >= 2 * E) ? 2 : ((e >= E) ? 1 : 0);
  int el = e - mp * E;
  const int* ep = (mp == 0) ? e0 : (mp == 1) ? e1 : e2;
  int s = ep[el], d = ep[el + E];
  int hb = (mp == 2) ? 2 * NG : mp * NG;                 // head/offsets base
  int tb = (mp == 0) ? 0 : (mp == 1) ? NG : NG + NP;     // tr3 segment base
  // |tl+tr| <= sum|qw| ~ 10 -> exp safe in fp32 without max-shift.
  float w = expf((tl3[hb + s] + tr3[tb + d]) * sharp[mp]);
  recs[offsets[hb + s] + rank[e]] = make_int2(d << 8, __float_as_int(w));
}

// ------- fused gather + relation combine: QUARTER per OUTPUT node ---------
__global__ __launch_bounds__(256) void gather_combine(
    const ushort* __restrict__ rb_gene, const ushort* __restrict__ rb_prot,
    const ushort* __restrict__ lb_gene, const ushort* __restrict__ lb_prot,
    const int* __restrict__ offsets, const int2* __restrict__ recs,
    const float* __restrict__ cgW, const float* __restrict__ cgb,
    const float* __restrict__ cpW, const float* __restrict__ cpb,
    float* __restrict__ out_gene, float* __restrict__ out_prot,
    int NG, int NP) {
  const int lane = threadIdx.x & 63;
  const int l16 = lane & 15;
  const int node = blockIdx.x * 16 + (threadIdx.x >> 4);
  if (node >= NG + NP) return;
  const bool isGene = node < NG;
  const unsigned coloff = (unsigned)l16 << 4;   // 16 B per lane
  const unsigned OMASK = 0x00FFFF00u;           // bounds stray row offsets

  const int h0 = isGene ? node : NG + node;     // gg for genes / pp for prots
  const int j0a = offsets[h0];
  const int ca = offsets[h0 + 1] - j0a;
  int j0b = 0, cb2 = 0;
  if (isGene) {
    j0b = offsets[NG + node];
    cb2 = offsets[NG + node + 1] - j0b;
  }

  float a0[8] = {0.f, 0.f, 0.f, 0.f, 0.f, 0.f, 0.f, 0.f};
  float a1[8] = {0.f, 0.f, 0.f, 0.f, 0.f, 0.f, 0.f, 0.f};
  float ds0 = 0.f, ds1 = 0.f;
  const ushort* rtA = isGene ? rb_gene : rb_prot;

  if (isGene) {
    const int cmax = (ca > cb2) ? ca : cb2;
    if (cmax > 0) {
      int2 rA[4], rB[4];
#pragma unroll
      for (int p = 0; p < 4; ++p) {
        rA[p] = recs[j0a + ((p < ca) ? p : 0)];
        rB[p] = recs[j0b + ((p < cb2) ? p : 0)];
      }
      const int nit = (cmax + 3) >> 2;
      for (int it = 0; it < nit; ++it) {
        const int b = it * 4;
        float wA[4], wB[4];
        uint4 vA[4], vB[4];
#pragma unroll
        for (int p = 0; p < 4; ++p) {
          wA[p] = (b + p < ca)  ? __int_as_float(rA[p].y) : 0.f;
          wB[p] = (b + p < cb2) ? __int_as_float(rB[p].y) : 0.f;
          vA[p] = *(const uint4*)((const char*)rtA + (((unsigned)rA[p].x & OMASK) + coloff));
          vB[p] = *(const uint4*)((const char*)rb_prot + (((unsigned)rB[p].x & OMASK) + coloff));
        }
        const int nb = b + 4;
#pragma unroll
        for (int p = 0; p < 4; ++p) {
          rA[p] = recs[j0a + ((nb + p < ca) ? nb + p : 0)];
          rB[p] = recs[j0b + ((nb + p < cb2) ? nb + p : 0)];
        }
#pragma unroll
        for (int p = 0; p < 4; ++p) {
          ds0 += wA[p];
          a0[0] += b2f_lo(vA[p].x) * wA[p]; a0[1] += b2f_hi(vA[p].x) * wA[p];
          a0[2] += b2f_lo(vA[p].y) * wA[p]; a0[3] += b2f_hi(vA[p].y) * wA[p];
          a0[4] += b2f_lo(vA[p].z) * wA[p]; a0[5] += b2f_hi(vA[p].z) * wA[p];
          a0[6] += b2f_lo(vA[p].w) * wA[p]; a0[7] += b2f_hi(vA[p].w) * wA[p];
          ds1 += wB[p];
          a1[0] += b2f_lo(vB[p].x) * wB[p]; a1[1] += b2f_hi(vB[p].x) * wB[p];
          a1[2] += b2f_lo(vB[p].y) * wB[p]; a1[3] += b2f_hi(vB[p].y) * wB[p];
          a1[4] += b2f_lo(vB[p].z) * wB[p]; a1[5] += b2f_hi(vB[p].z) * wB[p];
          a1[6] += b2f_lo(vB[p].w) * wB[p]; a1[7] += b2f_hi(vB[p].w) * wB[p];
        }
      }
    }
  } else {
    if (ca > 0) {
      int2 r0 = recs[j0a];
      int2 r1 = recs[j0a + ((1 < ca) ? 1 : 0)];
      int2 r2 = recs[j0a + ((2 < ca) ? 2 : 0)];
      int2 r3 = recs[j0a + ((3 < ca) ? 3 : 0)];
      const int nit = (ca + 3) >> 2;
      for (int it = 0; it < nit; ++it) {
        const int b = it * 4;
        const float w0 = (b < ca)     ? __int_as_float(r0.y) : 0.f;
        const float w1 = (b + 1 < ca) ? __int_as_float(r1.y) : 0.f;
        const float w2 = (b + 2 < ca) ? __int_as_float(r2.y) : 0.f;
        const float w3 = (b + 3 < ca) ? __int_as_float(r3.y) : 0.f;
        const uint4 v0 = *(const uint4*)((const char*)rtA + (((unsigned)r0.x & OMASK) + coloff));
        const uint4 v1 = *(const uint4*)((const char*)rtA + (((unsigned)r1.x & OMASK) + coloff));
        const uint4 v2 = *(const uint4*)((const char*)rtA + (((unsigned)r2.x & OMASK) + coloff));
        const uint4 v3 = *(const uint4*)((const char*)rtA + (((unsigned)r3.x & OMASK) + coloff));
        const int nb = b + 4;
        r0 = recs[j0a + ((nb < ca) ? nb : 0)];
        r1 = recs[j0a + ((nb + 1 < ca) ? nb + 1 : 0)];
        r2 = recs[j0a + ((nb + 2 < ca) ? nb + 2 : 0)];
        r3 = recs[j0a + ((nb + 3 < ca) ? nb + 3 : 0)];
        ds0 += (w0 + w1) + (w2 + w3);
        a0[0] += b2f_lo(v0.x) * w0 + b2f_lo(v1.x) * w1 + b2f_lo(v2.x) * w2 + b2f_lo(v3.x) * w3;
        a0[1] += b2f_hi(v0.x) * w0 + b2f_hi(v1.x) * w1 + b2f_hi(v2.x) * w2 + b2f_hi(v3.x) * w3;
        a0[2] += b2f_lo(v0.y) * w0 + b2f_lo(v1.y) * w1 + b2f_lo(v2.y) * w2 + b2f_lo(v3.y) * w3;
        a0[3] += b2f_hi(v0.y) * w0 + b2f_hi(v1.y) * w1 + b2f_hi(v2.y) * w2 + b2f_hi(v3.y) * w3;
        a0[4] += b2f_lo(v0.z) * w0 + b2f_lo(v1.z) * w1 + b2f_lo(v2.z) * w2 + b2f_lo(v3.z) * w3;
        a0[5] += b2f_hi(v0.z) * w0 + b2f_hi(v1.z) * w1 + b2f_hi(v2.z) * w2 + b2f_hi(v3.z) * w3;
        a0[6] += b2f_lo(v0.w) * w0 + b2f_lo(v1.w) * w1 + b2f_lo(v2.w) * w2 + b2f_lo(v3.w) * w3;
        a0[7] += b2f_hi(v0.w) * w0 + b2f_hi(v1.w) * w1 + b2f_hi(v2.w) * w2 + b2f_hi(v3.w) * w3;
      }
    }
  }

  // ---- epilogue (per quarter; ds is lane-uniform within the quarter) ----
  const float inv0 = 1.f / (ds0 + 1e-16f);
  const float inv1 = 1.f / (ds1 + 1e-16f);
  float g0[8], g1[8], self[8];
#pragma unroll
  for (int c = 0; c < 8; ++c) { g0[c] = a0[c] * inv0; g1[c] = a1[c] * inv1; }
  {
    const ushort* lbp = isGene ? lb_gene + (size_t)node * 128
                               : lb_prot + (size_t)(node - NG) * 128;
    uint4 sv = *(const uint4*)(lbp + l16 * 8);
    self[0] = b2f_lo(sv.x); self[1] = b2f_hi(sv.x);
    self[2] = b2f_lo(sv.y); self[3] = b2f_hi(sv.y);
    self[4] = b2f_lo(sv.z); self[5] = b2f_hi(sv.z);
    self[6] = b2f_lo(sv.w); self[7] = b2f_hi(sv.w);
  }

  const float* cW = isGene ? cgW : cpW;
  const float cb = isGene ? cgb[0] : cpb[0];
  const float4 wlo = *(const float4*)(cW + l16 * 8);
  const float4 whi = *(const float4*)(cW + l16 * 8 + 4);
  float p0 = g0[0] * wlo.x + g0[1] * wlo.y + g0[2] * wlo.z + g0[3] * wlo.w +
             g0[4] * whi.x + g0[5] * whi.y + g0[6] * whi.z + g0[7] * whi.w;
  float p1 = g1[0] * wlo.x + g1[1] * wlo.y + g1[2] * wlo.z + g1[3] * wlo.w +
             g1[4] * whi.x + g1[5] * whi.y + g1[6] * whi.z + g1[7] * whi.w;
  float ps = self[0] * wlo.x + self[1] * wlo.y + self[2] * wlo.z + self[3] * wlo.w +
             self[4] * whi.x + self[5] * whi.y + self[6] * whi.z + self[7] * whi.w;
#pragma unroll
  for (int m = 8; m >= 1; m >>= 1) {  // reduce the quarter's 16 col-lanes
    p0 += __shfl_xor(p0, m, 64);
    p1 += __shfl_xor(p1, m, 64);
    ps += __shfl_xor(ps, m, 64);
  }
  const float s0 = p0 + cb, s1 = p1 + cb, ss = ps + cb;
  const float mx = isGene ? fmaxf(fmaxf(s0, s1), ss) : fmaxf(s0, ss);
  const float e0 = expf(s0 - mx);
  const float e1 = isGene ? expf(s1 - mx) : 0.f;
  const float es = expf(ss - mx);
  const float sum = e0 + e1 + es;
  const float b0 = e0 / sum, b1 = e1 / sum, bs = es / sum;

  float4 o0, o1;
  o0.x = fmaxf(g0[0] * b0 + g1[0] * b1 + self[0] * bs, 0.f);
  o0.y = fmaxf(g0[1] * b0 + g1[1] * b1 + self[1] * bs, 0.f);
  o0.z = fmaxf(g0[2] * b0 + g1[2] * b1 + self[2] * bs, 0.f);
  o0.w = fmaxf(g0[3] * b0 + g1[3] * b1 + self[3] * bs, 0.f);
  o1.x = fmaxf(g0[4] * b0 + g1[4] * b1 + self[4] * bs, 0.f);
  o1.y = fmaxf(g0[5] * b0 + g1[5] * b1 + self[5] * bs, 0.f);
  o1.z = fmaxf(g0[6] * b0 + g1[6] * b1 + self[6] * bs, 0.f);
  o1.w = fmaxf(g0[7] * b0 + g1[7] * b1 + self[7] * bs, 0.f);
  float* op = isGene ? out_gene + (size_t)node * 128
                     : out_prot + (size_t)(node - NG) * 128;
  *(float4*)(op + l16 * 8) = o0;
  *(float4*)(op + l16 * 8 + 4) = o1;
}

// ---------------------------------------------------------------------------
extern "C" void kernel_launch(void* const* d_in, const int* in_sizes, int n_in,
                              void* d_out, int out_size, void* d_ws,
                              size_t ws_size, hipStream_t stream) {
  const float* x_gene  = (const float*)d_in[0];
  const float* x_prot  = (const float*)d_in[1];
  const float* Wl_gene = (const float*)d_in[2];
  const float* bl_gene = (const float*)d_in[3];
  const float* Wr_gene = (const float*)d_in[4];
  const float* br_gene = (const float*)d_in[5];
  const float* Wl_prot = (const float*)d_in[6];
  const float* bl_prot = (const float*)d_in[7];
  const float* Wr_prot = (const float*)d_in[8];
  const float* br_prot = (const float*)d_in[9];
  const float* alW     = (const float*)d_in[10];  // [3,32,128] contiguous
  const float* alb     = (const float*)d_in[11];  // [3,32] contiguous
  const float* arW     = (const float*)d_in[12];
  const float* arb     = (const float*)d_in[13];
  const float* qw      = (const float*)d_in[14];  // [3,64,1]
  const float* sharp   = (const float*)d_in[15];
  const float* cgW     = (const float*)d_in[16];
  const float* cgb     = (const float*)d_in[17];
  const float* cpW     = (const float*)d_in[18];
  const float* cpb     = (const float*)d_in[19];
  const int* e_gg      = (const int*)d_in[20];
  const int* e_gp      = (const int*)d_in[21];
  const int* e_pp      = (const int*)d_in[22];

  const int NG = in_sizes[0] / 256;
  const int NP = in_sizes[1] / 256;
  const int E  = in_sizes[20] / 2;
  const int NPG = (NG + 127) & ~127;
  const int NT = 2 * NG + NP;          // concatenated head-node space
  const int NR = NG + 2 * NP;          // concatenated tail-node space (tr)

  char* base = (char*)d_ws;
  size_t off = 0;
  auto alloc = [&](size_t bytes) {
    void* p = base + off;
    off = (off + bytes + 255) & ~(size_t)255;
    return p;
  };
  ushort* Wlr_gene = (ushort*)alloc(256 * 256 * 2);
  ushort* Wlr_prot = (ushort*)alloc(256 * 256 * 2);
  ushort* alWb     = (ushort*)alloc(96 * 128 * 2);
  ushort* arWb     = (ushort*)alloc(96 * 128 * 2);
  ushort* lb_gene  = (ushort*)alloc((size_t)NPG * 128 * 2);
  ushort* rb_gene  = (ushort*)alloc((size_t)NPG * 128 * 2);
  ushort* lb_prot  = (ushort*)alloc((size_t)NPG * 128 * 2);
  ushort* rb_prot  = (ushort*)alloc((size_t)NPG * 128 * 2);
  int*    deg      = (int*)alloc((size_t)NT * 4);
  int*    offsets  = (int*)alloc((size_t)(NT + 1) * 4);
  const int TILES  = (NT + 2047) / 2048;
  int*    tile_tot = (int*)alloc((size_t)TILES * 4);
  int*    tile_pre = (int*)alloc((size_t)TILES * 4);
  int*    rank     = (int*)alloc((size_t)(3 * E) * 4);
  int2*   recs     = (int2*)alloc((size_t)(3 * E) * sizeof(int2));
  float*  tl3      = (float*)alloc((size_t)NT * 4);
  float*  tr3      = (float*)alloc((size_t)NR * 4);

  float* out_gene = (float*)d_out;
  float* out_prot = out_gene + (size_t)NG * 128;

  dim3 blk(256);

  // ---- 0) deg memset (must precede fused hist) + weight conversions ----
  hipMemsetAsync(deg, 0, (size_t)NT * sizeof(int), stream);
  {
    CvtArgs a;
    const float* srcs[8] = {Wl_gene, Wr_gene, Wl_prot, Wr_prot, alW, arW,
                            Wl_gene, Wl_gene};
    ushort* dsts[8] = {Wlr_gene, Wlr_gene + 128 * 256,
                       Wlr_prot, Wlr_prot + 128 * 256, alWb, arWb,
                       Wlr_gene, Wlr_gene};
    int sizes[8] = {128 * 256, 128 * 256, 128 * 256, 128 * 256,
                    96 * 128, 96 * 128, 0, 0};
    int b = 0;
    for (int j = 0; j < 8; ++j) {
      a.src[j] = srcs[j]; a.dst[j] = dsts[j];
      a.valid[j] = sizes[j]; a.total[j] = sizes[j];
      a.bstart[j] = b;
      b += (sizes[j] / 4 + 255) / 256;
    }
    a.bstart[8] = b;
    cvt_multi<<<b, blk, 0, stream>>>(a);
  }

  // ---- 1) fused proj + attn tanh-dot + edge histogram (1 dispatch) ----
  const int gridE3 = (3 * E + 255) / 256;
  const int projBlocks = (NPG / 128) * 4;
  {
    ProjArgs p;
    p.x[0] = x_gene; p.x[1] = x_prot;
    p.Wb[0] = Wlr_gene; p.Wb[1] = Wlr_prot;
    p.bl[0] = bl_gene; p.bl[1] = bl_prot;
    p.br[0] = br_gene; p.br[1] = br_prot;
    p.lb[0] = lb_gene; p.lb[1] = lb_prot;
    p.rb[0] = rb_gene; p.rb[1] = rb_prot;
    p.N[0] = NG; p.N[1] = NP;
    // attn entries: e = ty*2 + colHalf
    p.aW[0] = alWb;            p.ab[0] = alb;      p.BN[0] = 64;
    p.q0[0] = qw + 0;  p.q1[0] = qw + 64;  p.o0[0] = tl3;          p.o1[0] = tl3 + NG;
    p.aW[1] = arWb;            p.ab[1] = arb;      p.BN[1] = 32;
    p.q0[1] = qw + 32; p.q1[1] = qw + 32;  p.o0[1] = tr3;          p.o1[1] = tr3;
    p.aW[2] = alWb + 64 * 128; p.ab[2] = alb + 64; p.BN[2] = 32;
    p.q0[2] = qw + 128; p.q1[2] = qw + 128; p.o0[2] = tl3 + 2 * NG; p.o1[2] = tl3 + 2 * NG;
    p.aW[3] = arWb + 32 * 128; p.ab[3] = arb + 32; p.BN[3] = 64;
    p.q0[3] = qw + 96; p.q1[3] = qw + 160; p.o0[3] = tr3 + NG;     p.o1[3] = tr3 + NG + NP;
    // hist
    p.e0 = e_gg; p.e1 = e_gp; p.e2 = e_pp;
    p.deg = deg; p.rank = rank; p.E = E; p.NGh = NG;
    p.projBlocks = projBlocks;
    proj_lr_mfma<<<projBlocks + gridE3, blk, 0, stream>>>(p);
  }

  // ---- 2) CSR scan + scatter{d*256,w} ----
  scanA_kernel<<<TILES, blk, 0, stream>>>(deg, offsets, tile_tot, NT);
  scanB_kernel<<<1, blk, 0, stream>>>(tile_tot, tile_pre, offsets, TILES, NT);
  scanC_kernel<<<TILES, blk, 0, stream>>>(offsets, tile_pre, NT);
  scatter3_kernel<<<gridE3, blk, 0, stream>>>(e_gg, e_gp, e_pp, rank, offsets,
                                              tl3, tr3, sharp, recs, E, NG, NP);

  // ---- 3) fused gather + relation combine (1 dispatch) ----
  gather_combine<<<(NG + NP + 15) / 16, blk, 0, stream>>>(
      rb_gene, rb_prot, lb_gene, lb_prot, offsets, recs,
      cgW, cgb, cpW, cpb, out_gene, out_prot, NG, NP);
}

// Round 17
// 367.136 us; speedup vs baseline: 1.1482x; 1.0479x over previous
//
#include <hip/hip_runtime.h>
#include <hip/hip_bf16.h>

// ---------------------------------------------------------------------------
// LATTE heterogeneous GNN layer (gene/protein).
// R21 (resubmit; R16 bench was a GPU-acquisition timeout, no data):
//      INTERLEAVE proj and hist blocks (Bresenham: block bid is proj iff
//      floor((bid+1)P/T) > floor(bid*P/T)). R20 fused hist as TRAILING
//      blocks: HW dispatches in bid order, so all 1564 proj blocks ran
//      first and 5860 hist blocks tail-serialized (proj 84.5->141us,
//      recovered only 13 of hist's ~70us). Even 1-in-4.75 spacing keeps
//      ~1 proj + ~3 hist blocks co-resident per CU for the whole dispatch
//      -> hist's atomic latency hides under proj's 93%-idle issue slots.
//      Zero math changes (same proj body, same hist body; only bid->role
//      mapping). Everything else byte-identical to R20 (384.7us verified).
// ---------------------------------------------------------------------------

typedef __attribute__((ext_vector_type(8))) short short8;   // 8 bf16
typedef __attribute__((ext_vector_type(4))) float floatx4;  // 4 f32 acc

__device__ __forceinline__ void gload16(const void* g, void* l) {
  __builtin_amdgcn_global_load_lds(
      (const __attribute__((address_space(1))) void*)g,
      (__attribute__((address_space(3))) void*)l, 16, 0, 0);
}

__device__ __forceinline__ ushort f2b(float x) {
  __hip_bfloat16 h = __float2bfloat16(x);
  return *reinterpret_cast<ushort*>(&h);
}
__device__ __forceinline__ float b2f_lo(unsigned v) { return __uint_as_float(v << 16); }
__device__ __forceinline__ float b2f_hi(unsigned v) { return __uint_as_float(v & 0xffff0000u); }

// ---------------- batched fp32 -> bf16 convert (weights only) --------------
struct CvtArgs {
  const float* src[8];
  ushort* dst[8];
  int valid[8];
  int total[8];
  int bstart[9];
};
__global__ __launch_bounds__(256) void cvt_multi(CvtArgs a) {
  int b = blockIdx.x;
  int e = 0;
#pragma unroll
  for (int j = 1; j < 8; ++j)
    if (b >= a.bstart[j]) e = j;
  int i = ((b - a.bstart[e]) * 256 + threadIdx.x) * 4;
  if (i >= a.total[e]) return;
  float4 v = make_float4(0.f, 0.f, 0.f, 0.f);
  if (i < a.valid[e]) v = *(const float4*)(a.src[e] + i);
  ushort4 o;
  o.x = f2b(v.x); o.y = f2b(v.y); o.z = f2b(v.z); o.w = f2b(v.w);
  *(ushort4*)(a.dst[e] + i) = o;
}

// ------------- fused l/r projection + attn tanh-dot + edge histogram ------
// Bresenham-interleaved grid of T = projBlocks + histBlocks blocks.
// proj decode: projId -> ty = id&1, colHalf = (id>>1)&1, rowTile = id>>2.
struct ProjArgs {
  const float* x[2];
  const ushort* Wb[2];
  const float* bl[2];
  const float* br[2];
  ushort* lb[2];
  ushort* rb[2];
  int N[2];
  // fused attn entries, indexed e = ty*2 + colHalf
  const ushort* aW[4];
  const float* ab[4];
  const float* q0[4];   // cols 0..31
  const float* q1[4];   // cols 32..63 (BN=64 entries)
  float* o0[4];
  float* o1[4];
  int BN[4];
  // fused hist3
  const int* e0;
  const int* e1;
  const int* e2;
  int* deg;
  int* rank;
  int E;
  int NGh;
  int projBlocks;
  int totalBlocks;
};
__global__ __launch_bounds__(256) void proj_lr_mfma(ProjArgs g) {
  __shared__ float Asf[2 * 128 * 32];   // 2 x 16 KB fp32; attn tile aliases
  __shared__ ushort Bs[2 * 128 * 32];   // 2 x 8 KB bf16
  const int tid = threadIdx.x;

  // ---- Bresenham role decode: proj blocks spread evenly through grid ----
  const int P = g.projBlocks, T = g.totalBlocks;
  const int bid = blockIdx.x;
  const int pcntLo = (int)(((long long)bid * P) / T);
  const int pcntHi = (int)(((long long)(bid + 1) * P) / T);
  const bool isProj = pcntHi > pcntLo;

  // ---- fused hist3 path (uniform branch; no barriers touched) ----
  if (!isProj) {
    const int E = g.E;
    int e = (bid - pcntLo) * 256 + tid;   // histId = bid - projCountBefore
    if (e < 3 * E) {
      int mp = (e >= 2 * E) ? 2 : ((e >= E) ? 1 : 0);
      int el = e - mp * E;
      const int* ep = (mp == 0) ? g.e0 : (mp == 1) ? g.e1 : g.e2;
      int segb = (mp == 2) ? 2 * g.NGh : mp * g.NGh;
      g.rank[e] = atomicAdd(&g.deg[segb + ep[el]], 1);
    }
    return;
  }

  const int pb = pcntLo;                  // projId
  const int ty = pb & 1;
  const int colHalf = (pb >> 1) & 1;
  const float* xp = g.x[ty];
  const int N = g.N[ty];
  const int lane = tid & 63;
  const int wv = tid >> 6;
  const int wm = wv & 1, wn = wv >> 1;
  const int rowBase = (pb >> 2) * 128;
  const ushort* Wbase = g.Wb[ty] + (size_t)colHalf * 128 * 256;

  floatx4 acc[4][4] = {};

  auto stage = [&](int buf, int k0) {
#pragma unroll
    for (int i = 0; i < 4; ++i) {
      const int G = i * 256 + wv * 64 + lane;       // linear LDS granule
      const int row = G >> 3;
      const int cg = (G & 7) ^ (row & 7);           // preswizzled src chunk
      const int xr = min(rowBase + row, N - 1);
      gload16(xp + (size_t)xr * 256 + k0 + cg * 4, &Asf[buf * 4096 + G * 4]);
    }
#pragma unroll
    for (int i = 0; i < 2; ++i) {
      const int G = i * 256 + wv * 64 + lane;
      const int row = G >> 2;
      const int cg = (G & 3) ^ ((row >> 1) & 3);
      gload16(Wbase + (size_t)row * 256 + k0 + cg * 8, &Bs[buf * 4096 + G * 8]);
    }
  };

  stage(0, 0);
  __syncthreads();

  int t = 0;
  for (int k0 = 0; k0 < 256; k0 += 32) {
    if (k0 < 224) stage(t ^ 1, k0 + 32);
    const float* Ab = &Asf[t * 4096];
    const ushort* Bb = &Bs[t * 4096];
    short8 bf[4];
#pragma unroll
    for (int nt = 0; nt < 4; ++nt) {
      const int row = wn * 64 + nt * 16 + (lane & 15);
      const int c = (lane >> 4) ^ ((row >> 1) & 3);
      bf[nt] = *(const short8*)&Bb[(row * 4 + c) * 8];
    }
#pragma unroll
    for (int mt = 0; mt < 4; ++mt) {
      const int row = wm * 64 + mt * 16 + (lane & 15);
      const int c0 = ((lane >> 4) * 2) ^ (row & 7);
      const int c1 = ((lane >> 4) * 2 + 1) ^ (row & 7);
      float4 f0 = *(const float4*)&Ab[(row * 8 + c0) * 4];
      float4 f1 = *(const float4*)&Ab[(row * 8 + c1) * 4];
      short8 a;
      a[0] = (short)f2b(f0.x); a[1] = (short)f2b(f0.y);
      a[2] = (short)f2b(f0.z); a[3] = (short)f2b(f0.w);
      a[4] = (short)f2b(f1.x); a[5] = (short)f2b(f1.y);
      a[6] = (short)f2b(f1.z); a[7] = (short)f2b(f1.w);
#pragma unroll
      for (int nt = 0; nt < 4; ++nt)
        acc[mt][nt] = __builtin_amdgcn_mfma_f32_16x16x32_bf16(a, bf[nt], acc[mt][nt], 0, 0, 0);
    }
    __syncthreads();
    t ^= 1;
  }

  // ---- C-write to global + swizzled LDS tile (same bf16 bytes) ----
  ushort* tile = (ushort*)Asf;   // [row][swizzled chunk] 128x128 bf16
  const float* bias = colHalf ? g.br[ty] : g.bl[ty];
  ushort* outp = colHalf ? g.rb[ty] : g.lb[ty];
#pragma unroll
  for (int mt = 0; mt < 4; ++mt)
#pragma unroll
    for (int nt = 0; nt < 4; ++nt) {
      int col = wn * 64 + nt * 16 + (lane & 15);
      float bv = bias[col];
#pragma unroll
      for (int vi = 0; vi < 4; ++vi) {
        int row = wm * 64 + mt * 16 + (lane >> 4) * 4 + vi;   // local 0..127
        ushort v = f2b(acc[mt][nt][vi] + bv);
        tile[row * 128 + (((col >> 3) ^ (row & 15)) << 3) + (col & 7)] = v;
        if (rowBase + row < N) outp[(size_t)(rowBase + row) * 128 + col] = v;
      }
    }
  __syncthreads();   // tile visible to all waves

  // ---- attn projection + tanh-dot from LDS tile x global aW ----
  const int e = ty * 2 + colHalf;
  const int NB = g.BN[e] >> 4;
  const ushort* aW = g.aW[e];
  floatx4 acc2[2][4] = {};
  for (int k0 = 0; k0 < 128; k0 += 32) {
    short8 bf2[4];
#pragma unroll
    for (int nt = 0; nt < 4; ++nt)
      if (nt < NB)
        bf2[nt] = *(const short8*)(aW + (size_t)(nt * 16 + (lane & 15)) * 128 +
                                   k0 + (lane >> 4) * 8);
#pragma unroll
    for (int mt = 0; mt < 2; ++mt) {
      const int row = wv * 32 + mt * 16 + (lane & 15);
      const int c8 = (k0 >> 3) + (lane >> 4);          // chunk 0..15
      short8 a = *(const short8*)&tile[row * 128 + ((c8 ^ (row & 15)) << 3)];
#pragma unroll
      for (int nt = 0; nt < 4; ++nt)
        if (nt < NB)
          acc2[mt][nt] = __builtin_amdgcn_mfma_f32_16x16x32_bf16(a, bf2[nt], acc2[mt][nt], 0, 0, 0);
    }
  }

  const float* ab = g.ab[e];
  const int l15 = lane & 15;
  const bool two = (NB == 4);
  float bv2[4];
#pragma unroll
  for (int nt = 0; nt < 4; ++nt) bv2[nt] = (nt < NB) ? ab[nt * 16 + l15] : 0.f;
  float q0v0 = g.q0[e][l15], q0v1 = g.q0[e][16 + l15];
  float q1v0 = 0.f, q1v1 = 0.f;
  if (two) { q1v0 = g.q1[e][l15]; q1v1 = g.q1[e][16 + l15]; }
  float* o0 = g.o0[e];
  float* o1 = g.o1[e];
#pragma unroll
  for (int mt = 0; mt < 2; ++mt)
#pragma unroll
    for (int vi = 0; vi < 4; ++vi) {
      float slo = tanhf(acc2[mt][0][vi] + bv2[0]) * q0v0
                + tanhf(acc2[mt][1][vi] + bv2[1]) * q0v1;
      float shi = 0.f;
      if (two)
        shi = tanhf(acc2[mt][2][vi] + bv2[2]) * q1v0
            + tanhf(acc2[mt][3][vi] + bv2[3]) * q1v1;
#pragma unroll
      for (int m = 8; m >= 1; m >>= 1) {
        slo += __shfl_xor(slo, m, 64);   // xor<16 stays in the 16-lane group
        shi += __shfl_xor(shi, m, 64);
      }
      const int row = rowBase + wv * 32 + mt * 16 + (lane >> 4) * 4 + vi;
      if (l15 == 0 && row < N) {
        o0[row] = slo;
        if (two) o1[row] = shi;
      }
    }
}

// ------- hierarchical scan: A) tile scan, B) partials, C) add prefix ------
__global__ __launch_bounds__(256) void scanA_kernel(
    const int* __restrict__ deg, int* __restrict__ offsets,
    int* __restrict__ tile_tot, int n) {
  __shared__ int wtot[4];
  const int t = threadIdx.x;
  const int base = blockIdx.x * 2048 + t * 8;
  int v[8], pre[8], s = 0;
#pragma unroll
  for (int j = 0; j < 8; ++j) {
    v[j] = (base + j < n) ? deg[base + j] : 0;
    pre[j] = s;
    s += v[j];
  }
  const int lane = t & 63, wv = t >> 6;
  int x = s;
#pragma unroll
  for (int o = 1; o < 64; o <<= 1) {
    int u = __shfl_up(x, o, 64);
    if (lane >= o) x += u;
  }
  if (lane == 63) wtot[wv] = x;
  __syncthreads();
  int wpre = 0;
#pragma unroll
  for (int j = 0; j < 4; ++j) wpre += (j < wv) ? wtot[j] : 0;
  int excl = wpre + x - s;
#pragma unroll
  for (int j = 0; j < 8; ++j)
    if (base + j < n) offsets[base + j] = excl + pre[j];
  if (t == 255) tile_tot[blockIdx.x] = wpre + x;
}

__global__ __launch_bounds__(256) void scanB_kernel(
    const int* __restrict__ tile_tot, int* __restrict__ tile_pre,
    int* __restrict__ offsets, int T, int n) {
  __shared__ int wtot[4];
  const int t = threadIdx.x;
  int v = (t < T) ? tile_tot[t] : 0;
  const int lane = t & 63, wv = t >> 6;
  int x = v;
#pragma unroll
  for (int o = 1; o < 64; o <<= 1) {
    int u = __shfl_up(x, o, 64);
    if (lane >= o) x += u;
  }
  if (lane == 63) wtot[wv] = x;
  __syncthreads();
  int wpre = 0;
#pragma unroll
  for (int j = 0; j < 4; ++j) wpre += (j < wv) ? wtot[j] : 0;
  if (t < T) tile_pre[t] = wpre + x - v;
  if (t == 255) offsets[n] = wpre + x;  // grand total
}

__global__ __launch_bounds__(256) void scanC_kernel(
    int* __restrict__ offsets, const int* __restrict__ tile_pre, int n) {
  const int add = tile_pre[blockIdx.x];
  const int base = blockIdx.x * 2048 + threadIdx.x * 8;
#pragma unroll
  for (int j = 0; j < 8; ++j)
    if (base + j < n) offsets[base + j] += add;
}

// ------- scatter3: pos = offsets[node] + rank[e]; writes {d*256, w} -------
__global__ __launch_bounds__(256) void scatter3_kernel(
    const int* __restrict__ e0, const int* __restrict__ e1,
    const int* __restrict__ e2, const int* __restrict__ rank,
    const int* __restrict__ offsets,
    const float* __restrict__ tl3, const float* __restrict__ tr3,
    const float* __restrict__ sharp, int2* __restrict__ recs,
    int E, int NG, int NP) {
  int e = blockIdx.x * 256 + threadIdx.x;
  if (e >= 3 * E) return;
  int mp = (e >= 2 * E) ? 2 : ((e >= E) ? 1 : 0);
  int el = e - mp * E;
  const int* ep = (mp == 0) ? e0 : (mp == 1) ? e1 : e2;
  int s = ep[el], d = ep[el + E];
  int hb = (mp == 2) ? 2 * NG : mp * NG;                 // head/offsets base
  int tb = (mp == 0) ? 0 : (mp == 1) ? NG : NG + NP;     // tr3 segment base
  // |tl+tr| <= sum|qw| ~ 10 -> exp safe in fp32 without max-shift.
  float w = expf((tl3[hb + s] + tr3[tb + d]) * sharp[mp]);
  recs[offsets[hb + s] + rank[e]] = make_int2(d << 8, __float_as_int(w));
}

// ------- fused gather + relation combine: QUARTER per OUTPUT node ---------
__global__ __launch_bounds__(256) void gather_combine(
    const ushort* __restrict__ rb_gene, const ushort* __restrict__ rb_prot,
    const ushort* __restrict__ lb_gene, const ushort* __restrict__ lb_prot,
    const int* __restrict__ offsets, const int2* __restrict__ recs,
    const float* __restrict__ cgW, const float* __restrict__ cgb,
    const float* __restrict__ cpW, const float* __restrict__ cpb,
    float* __restrict__ out_gene, float* __restrict__ out_prot,
    int NG, int NP) {
  const int lane = threadIdx.x & 63;
  const int l16 = lane & 15;
  const int node = blockIdx.x * 16 + (threadIdx.x >> 4);
  if (node >= NG + NP) return;
  const bool isGene = node < NG;
  const unsigned coloff = (unsigned)l16 << 4;   // 16 B per lane
  const unsigned OMASK = 0x00FFFF00u;           // bounds stray row offsets

  const int h0 = isGene ? node : NG + node;     // gg for genes / pp for prots
  const int j0a = offsets[h0];
  const int ca = offsets[h0 + 1] - j0a;
  int j0b = 0, cb2 = 0;
  if (isGene) {
    j0b = offsets[NG + node];
    cb2 = offsets[NG + node + 1] - j0b;
  }

  float a0[8] = {0.f, 0.f, 0.f, 0.f, 0.f, 0.f, 0.f, 0.f};
  float a1[8] = {0.f, 0.f, 0.f, 0.f, 0.f, 0.f, 0.f, 0.f};
  float ds0 = 0.f, ds1 = 0.f;
  const ushort* rtA = isGene ? rb_gene : rb_prot;

  if (isGene) {
    const int cmax = (ca > cb2) ? ca : cb2;
    if (cmax > 0) {
      int2 rA[4], rB[4];
#pragma unroll
      for (int p = 0; p < 4; ++p) {
        rA[p] = recs[j0a + ((p < ca) ? p : 0)];
        rB[p] = recs[j0b + ((p < cb2) ? p : 0)];
      }
      const int nit = (cmax + 3) >> 2;
      for (int it = 0; it < nit; ++it) {
        const int b = it * 4;
        float wA[4], wB[4];
        uint4 vA[4], vB[4];
#pragma unroll
        for (int p = 0; p < 4; ++p) {
          wA[p] = (b + p < ca)  ? __int_as_float(rA[p].y) : 0.f;
          wB[p] = (b + p < cb2) ? __int_as_float(rB[p].y) : 0.f;
          vA[p] = *(const uint4*)((const char*)rtA + (((unsigned)rA[p].x & OMASK) + coloff));
          vB[p] = *(const uint4*)((const char*)rb_prot + (((unsigned)rB[p].x & OMASK) + coloff));
        }
        const int nb = b + 4;
#pragma unroll
        for (int p = 0; p < 4; ++p) {
          rA[p] = recs[j0a + ((nb + p < ca) ? nb + p : 0)];
          rB[p] = recs[j0b + ((nb + p < cb2) ? nb + p : 0)];
        }
#pragma unroll
        for (int p = 0; p < 4; ++p) {
          ds0 += wA[p];
          a0[0] += b2f_lo(vA[p].x) * wA[p]; a0[1] += b2f_hi(vA[p].x) * wA[p];
          a0[2] += b2f_lo(vA[p].y) * wA[p]; a0[3] += b2f_hi(vA[p].y) * wA[p];
          a0[4] += b2f_lo(vA[p].z) * wA[p]; a0[5] += b2f_hi(vA[p].z) * wA[p];
          a0[6] += b2f_lo(vA[p].w) * wA[p]; a0[7] += b2f_hi(vA[p].w) * wA[p];
          ds1 += wB[p];
          a1[0] += b2f_lo(vB[p].x) * wB[p]; a1[1] += b2f_hi(vB[p].x) * wB[p];
          a1[2] += b2f_lo(vB[p].y) * wB[p]; a1[3] += b2f_hi(vB[p].y) * wB[p];
          a1[4] += b2f_lo(vB[p].z) * wB[p]; a1[5] += b2f_hi(vB[p].z) * wB[p];
          a1[6] += b2f_lo(vB[p].w) * wB[p]; a1[7] += b2f_hi(vB[p].w) * wB[p];
        }
      }
    }
  } else {
    if (ca > 0) {
      int2 r0 = recs[j0a];
      int2 r1 = recs[j0a + ((1 < ca) ? 1 : 0)];
      int2 r2 = recs[j0a + ((2 < ca) ? 2 : 0)];
      int2 r3 = recs[j0a + ((3 < ca) ? 3 : 0)];
      const int nit = (ca + 3) >> 2;
      for (int it = 0; it < nit; ++it) {
        const int b = it * 4;
        const float w0 = (b < ca)     ? __int_as_float(r0.y) : 0.f;
        const float w1 = (b + 1 < ca) ? __int_as_float(r1.y) : 0.f;
        const float w2 = (b + 2 < ca) ? __int_as_float(r2.y) : 0.f;
        const float w3 = (b + 3 < ca) ? __int_as_float(r3.y) : 0.f;
        const uint4 v0 = *(const uint4*)((const char*)rtA + (((unsigned)r0.x & OMASK) + coloff));
        const uint4 v1 = *(const uint4*)((const char*)rtA + (((unsigned)r1.x & OMASK) + coloff));
        const uint4 v2 = *(const uint4*)((const char*)rtA + (((unsigned)r2.x & OMASK) + coloff));
        const uint4 v3 = *(const uint4*)((const char*)rtA + (((unsigned)r3.x & OMASK) + coloff));
        const int nb = b + 4;
        r0 = recs[j0a + ((nb < ca) ? nb : 0)];
        r1 = recs[j0a + ((nb + 1 < ca) ? nb + 1 : 0)];
        r2 = recs[j0a + ((nb + 2 < ca) ? nb + 2 : 0)];
        r3 = recs[j0a + ((nb + 3 < ca) ? nb + 3 : 0)];
        ds0 += (w0 + w1) + (w2 + w3);
        a0[0] += b2f_lo(v0.x) * w0 + b2f_lo(v1.x) * w1 + b2f_lo(v2.x) * w2 + b2f_lo(v3.x) * w3;
        a0[1] += b2f_hi(v0.x) * w0 + b2f_hi(v1.x) * w1 + b2f_hi(v2.x) * w2 + b2f_hi(v3.x) * w3;
        a0[2] += b2f_lo(v0.y) * w0 + b2f_lo(v1.y) * w1 + b2f_lo(v2.y) * w2 + b2f_lo(v3.y) * w3;
        a0[3] += b2f_hi(v0.y) * w0 + b2f_hi(v1.y) * w1 + b2f_hi(v2.y) * w2 + b2f_hi(v3.y) * w3;
        a0[4] += b2f_lo(v0.z) * w0 + b2f_lo(v1.z) * w1 + b2f_lo(v2.z) * w2 + b2f_lo(v3.z) * w3;
        a0[5] += b2f_hi(v0.z) * w0 + b2f_hi(v1.z) * w1 + b2f_hi(v2.z) * w2 + b2f_hi(v3.z) * w3;
        a0[6] += b2f_lo(v0.w) * w0 + b2f_lo(v1.w) * w1 + b2f_lo(v2.w) * w2 + b2f_lo(v3.w) * w3;
        a0[7] += b2f_hi(v0.w) * w0 + b2f_hi(v1.w) * w1 + b2f_hi(v2.w) * w2 + b2f_hi(v3.w) * w3;
      }
    }
  }

  // ---- epilogue (per quarter; ds is lane-uniform within the quarter) ----
  const float inv0 = 1.f / (ds0 + 1e-16f);
  const float inv1 = 1.f / (ds1 + 1e-16f);
  float g0[8], g1[8], self[8];
#pragma unroll
  for (int c = 0; c < 8; ++c) { g0[c] = a0[c] * inv0; g1[c] = a1[c] * inv1; }
  {
    const ushort* lbp = isGene ? lb_gene + (size_t)node * 128
                               : lb_prot + (size_t)(node - NG) * 128;
    uint4 sv = *(const uint4*)(lbp + l16 * 8);
    self[0] = b2f_lo(sv.x); self[1] = b2f_hi(sv.x);
    self[2] = b2f_lo(sv.y); self[3] = b2f_hi(sv.y);
    self[4] = b2f_lo(sv.z); self[5] = b2f_hi(sv.z);
    self[6] = b2f_lo(sv.w); self[7] = b2f_hi(sv.w);
  }

  const float* cW = isGene ? cgW : cpW;
  const float cb = isGene ? cgb[0] : cpb[0];
  const float4 wlo = *(const float4*)(cW + l16 * 8);
  const float4 whi = *(const float4*)(cW + l16 * 8 + 4);
  float p0 = g0[0] * wlo.x + g0[1] * wlo.y + g0[2] * wlo.z + g0[3] * wlo.w +
             g0[4] * whi.x + g0[5] * whi.y + g0[6] * whi.z + g0[7] * whi.w;
  float p1 = g1[0] * wlo.x + g1[1] * wlo.y + g1[2] * wlo.z + g1[3] * wlo.w +
             g1[4] * whi.x + g1[5] * whi.y + g1[6] * whi.z + g1[7] * whi.w;
  float ps = self[0] * wlo.x + self[1] * wlo.y + self[2] * wlo.z + self[3] * wlo.w +
             self[4] * whi.x + self[5] * whi.y + self[6] * whi.z + self[7] * whi.w;
#pragma unroll
  for (int m = 8; m >= 1; m >>= 1) {  // reduce the quarter's 16 col-lanes
    p0 += __shfl_xor(p0, m, 64);
    p1 += __shfl_xor(p1, m, 64);
    ps += __shfl_xor(ps, m, 64);
  }
  const float s0 = p0 + cb, s1 = p1 + cb, ss = ps + cb;
  const float mx = isGene ? fmaxf(fmaxf(s0, s1), ss) : fmaxf(s0, ss);
  const float e0 = expf(s0 - mx);
  const float e1 = isGene ? expf(s1 - mx) : 0.f;
  const float es = expf(ss - mx);
  const float sum = e0 + e1 + es;
  const float b0 = e0 / sum, b1 = e1 / sum, bs = es / sum;

  float4 o0, o1;
  o0.x = fmaxf(g0[0] * b0 + g1[0] * b1 + self[0] * bs, 0.f);
  o0.y = fmaxf(g0[1] * b0 + g1[1] * b1 + self[1] * bs, 0.f);
  o0.z = fmaxf(g0[2] * b0 + g1[2] * b1 + self[2] * bs, 0.f);
  o0.w = fmaxf(g0[3] * b0 + g1[3] * b1 + self[3] * bs, 0.f);
  o1.x = fmaxf(g0[4] * b0 + g1[4] * b1 + self[4] * bs, 0.f);
  o1.y = fmaxf(g0[5] * b0 + g1[5] * b1 + self[5] * bs, 0.f);
  o1.z = fmaxf(g0[6] * b0 + g1[6] * b1 + self[6] * bs, 0.f);
  o1.w = fmaxf(g0[7] * b0 + g1[7] * b1 + self[7] * bs, 0.f);
  float* op = isGene ? out_gene + (size_t)node * 128
                     : out_prot + (size_t)(node - NG) * 128;
  *(float4*)(op + l16 * 8) = o0;
  *(float4*)(op + l16 * 8 + 4) = o1;
}

// ---------------------------------------------------------------------------
extern "C" void kernel_launch(void* const* d_in, const int* in_sizes, int n_in,
                              void* d_out, int out_size, void* d_ws,
                              size_t ws_size, hipStream_t stream) {
  const float* x_gene  = (const float*)d_in[0];
  const float* x_prot  = (const float*)d_in[1];
  const float* Wl_gene = (const float*)d_in[2];
  const float* bl_gene = (const float*)d_in[3];
  const float* Wr_gene = (const float*)d_in[4];
  const float* br_gene = (const float*)d_in[5];
  const float* Wl_prot = (const float*)d_in[6];
  const float* bl_prot = (const float*)d_in[7];
  const float* Wr_prot = (const float*)d_in[8];
  const float* br_prot = (const float*)d_in[9];
  const float* alW     = (const float*)d_in[10];  // [3,32,128] contiguous
  const float* alb     = (const float*)d_in[11];  // [3,32] contiguous
  const float* arW     = (const float*)d_in[12];
  const float* arb     = (const float*)d_in[13];
  const float* qw      = (const float*)d_in[14];  // [3,64,1]
  const float* sharp   = (const float*)d_in[15];
  const float* cgW     = (const float*)d_in[16];
  const float* cgb     = (const float*)d_in[17];
  const float* cpW     = (const float*)d_in[18];
  const float* cpb     = (const float*)d_in[19];
  const int* e_gg      = (const int*)d_in[20];
  const int* e_gp      = (const int*)d_in[21];
  const int* e_pp      = (const int*)d_in[22];

  const int NG = in_sizes[0] / 256;
  const int NP = in_sizes[1] / 256;
  const int E  = in_sizes[20] / 2;
  const int NPG = (NG + 127) & ~127;
  const int NT = 2 * NG + NP;          // concatenated head-node space
  const int NR = NG + 2 * NP;          // concatenated tail-node space (tr)

  char* base = (char*)d_ws;
  size_t off = 0;
  auto alloc = [&](size_t bytes) {
    void* p = base + off;
    off = (off + bytes + 255) & ~(size_t)255;
    return p;
  };
  ushort* Wlr_gene = (ushort*)alloc(256 * 256 * 2);
  ushort* Wlr_prot = (ushort*)alloc(256 * 256 * 2);
  ushort* alWb     = (ushort*)alloc(96 * 128 * 2);
  ushort* arWb     = (ushort*)alloc(96 * 128 * 2);
  ushort* lb_gene  = (ushort*)alloc((size_t)NPG * 128 * 2);
  ushort* rb_gene  = (ushort*)alloc((size_t)NPG * 128 * 2);
  ushort* lb_prot  = (ushort*)alloc((size_t)NPG * 128 * 2);
  ushort* rb_prot  = (ushort*)alloc((size_t)NPG * 128 * 2);
  int*    deg      = (int*)alloc((size_t)NT * 4);
  int*    offsets  = (int*)alloc((size_t)(NT + 1) * 4);
  const int TILES  = (NT + 2047) / 2048;
  int*    tile_tot = (int*)alloc((size_t)TILES * 4);
  int*    tile_pre = (int*)alloc((size_t)TILES * 4);
  int*    rank     = (int*)alloc((size_t)(3 * E) * 4);
  int2*   recs     = (int2*)alloc((size_t)(3 * E) * sizeof(int2));
  float*  tl3      = (float*)alloc((size_t)NT * 4);
  float*  tr3      = (float*)alloc((size_t)NR * 4);

  float* out_gene = (float*)d_out;
  float* out_prot = out_gene + (size_t)NG * 128;

  dim3 blk(256);

  // ---- 0) deg memset (must precede fused hist) + weight conversions ----
  hipMemsetAsync(deg, 0, (size_t)NT * sizeof(int), stream);
  {
    CvtArgs a;
    const float* srcs[8] = {Wl_gene, Wr_gene, Wl_prot, Wr_prot, alW, arW,
                            Wl_gene, Wl_gene};
    ushort* dsts[8] = {Wlr_gene, Wlr_gene + 128 * 256,
                       Wlr_prot, Wlr_prot + 128 * 256, alWb, arWb,
                       Wlr_gene, Wlr_gene};
    int sizes[8] = {128 * 256, 128 * 256, 128 * 256, 128 * 256,
                    96 * 128, 96 * 128, 0, 0};
    int b = 0;
    for (int j = 0; j < 8; ++j) {
      a.src[j] = srcs[j]; a.dst[j] = dsts[j];
      a.valid[j] = sizes[j]; a.total[j] = sizes[j];
      a.bstart[j] = b;
      b += (sizes[j] / 4 + 255) / 256;
    }
    a.bstart[8] = b;
    cvt_multi<<<b, blk, 0, stream>>>(a);
  }

  // ---- 1) fused proj + attn + hist, Bresenham-interleaved (1 dispatch) ----
  const int gridE3 = (3 * E + 255) / 256;
  const int projBlocks = (NPG / 128) * 4;
  {
    ProjArgs p;
    p.x[0] = x_gene; p.x[1] = x_prot;
    p.Wb[0] = Wlr_gene; p.Wb[1] = Wlr_prot;
    p.bl[0] = bl_gene; p.bl[1] = bl_prot;
    p.br[0] = br_gene; p.br[1] = br_prot;
    p.lb[0] = lb_gene; p.lb[1] = lb_prot;
    p.rb[0] = rb_gene; p.rb[1] = rb_prot;
    p.N[0] = NG; p.N[1] = NP;
    // attn entries: e = ty*2 + colHalf
    p.aW[0] = alWb;            p.ab[0] = alb;      p.BN[0] = 64;
    p.q0[0] = qw + 0;  p.q1[0] = qw + 64;  p.o0[0] = tl3;          p.o1[0] = tl3 + NG;
    p.aW[1] = arWb;            p.ab[1] = arb;      p.BN[1] = 32;
    p.q0[1] = qw + 32; p.q1[1] = qw + 32;  p.o0[1] = tr3;          p.o1[1] = tr3;
    p.aW[2] = alWb + 64 * 128; p.ab[2] = alb + 64; p.BN[2] = 32;
    p.q0[2] = qw + 128; p.q1[2] = qw + 128; p.o0[2] = tl3 + 2 * NG; p.o1[2] = tl3 + 2 * NG;
    p.aW[3] = arWb + 32 * 128; p.ab[3] = arb + 32; p.BN[3] = 64;
    p.q0[3] = qw + 96; p.q1[3] = qw + 160; p.o0[3] = tr3 + NG;     p.o1[3] = tr3 + NG + NP;
    // hist
    p.e0 = e_gg; p.e1 = e_gp; p.e2 = e_pp;
    p.deg = deg; p.rank = rank; p.E = E; p.NGh = NG;
    p.projBlocks = projBlocks;
    p.totalBlocks = projBlocks + gridE3;
    proj_lr_mfma<<<projBlocks + gridE3, blk, 0, stream>>>(p);
  }

  // ---- 2) CSR scan + scatter{d*256,w} ----
  scanA_kernel<<<TILES, blk, 0, stream>>>(deg, offsets, tile_tot, NT);
  scanB_kernel<<<1, blk, 0, stream>>>(tile_tot, tile_pre, offsets, TILES, NT);
  scanC_kernel<<<TILES, blk, 0, stream>>>(offsets, tile_pre, NT);
  scatter3_kernel<<<gridE3, blk, 0, stream>>>(e_gg, e_gp, e_pp, rank, offsets,
                                              tl3, tr3, sharp, recs, E, NG, NP);

  // ---- 3) fused gather + relation combine (1 dispatch) ----
  gather_combine<<<(NG + NP + 15) / 16, blk, 0, stream>>>(
      rb_gene, rb_prot, lb_gene, lb_prot, offsets, recs,
      cgW, cgb, cpW, cpb, out_gene, out_prot, NG, NP);
}

// Round 18
// 362.575 us; speedup vs baseline: 1.1627x; 1.0126x over previous
//
#include <hip/hip_runtime.h>
#include <hip/hip_bf16.h>

// ---------------------------------------------------------------------------
// LATTE heterogeneous GNN layer (gene/protein).
// R22: tl CANCELS in the per-head softmax (exp((tl+tr)s)/sum = exp(tr*s)/sum)
//      -> (a) al-projection attn tails deleted (colHalf==0 blocks skip the
//      tile deposit + tail entirely); (b) tr3 stores exp(tr*sharp) at write
//      time (segment known per entry) so scatter3 loses BOTH its tl3 random
//      read and the expf. Mathematically identical alpha; ~1ulp FP delta.
//      Everything else byte-identical to R21 (367.1us verified: Bresenham
//      proj+hist interleave 114.6us, gather 69, scans ~15).
// ---------------------------------------------------------------------------

typedef __attribute__((ext_vector_type(8))) short short8;   // 8 bf16
typedef __attribute__((ext_vector_type(4))) float floatx4;  // 4 f32 acc

__device__ __forceinline__ void gload16(const void* g, void* l) {
  __builtin_amdgcn_global_load_lds(
      (const __attribute__((address_space(1))) void*)g,
      (__attribute__((address_space(3))) void*)l, 16, 0, 0);
}

__device__ __forceinline__ ushort f2b(float x) {
  __hip_bfloat16 h = __float2bfloat16(x);
  return *reinterpret_cast<ushort*>(&h);
}
__device__ __forceinline__ float b2f_lo(unsigned v) { return __uint_as_float(v << 16); }
__device__ __forceinline__ float b2f_hi(unsigned v) { return __uint_as_float(v & 0xffff0000u); }

// ---------------- batched fp32 -> bf16 convert (weights only) --------------
struct CvtArgs {
  const float* src[8];
  ushort* dst[8];
  int valid[8];
  int total[8];
  int bstart[9];
};
__global__ __launch_bounds__(256) void cvt_multi(CvtArgs a) {
  int b = blockIdx.x;
  int e = 0;
#pragma unroll
  for (int j = 1; j < 8; ++j)
    if (b >= a.bstart[j]) e = j;
  int i = ((b - a.bstart[e]) * 256 + threadIdx.x) * 4;
  if (i >= a.total[e]) return;
  float4 v = make_float4(0.f, 0.f, 0.f, 0.f);
  if (i < a.valid[e]) v = *(const float4*)(a.src[e] + i);
  ushort4 o;
  o.x = f2b(v.x); o.y = f2b(v.y); o.z = f2b(v.z); o.w = f2b(v.w);
  *(ushort4*)(a.dst[e] + i) = o;
}

// ------------- fused l/r projection + attn tanh-dot + edge histogram ------
// Bresenham-interleaved grid of T = projBlocks + histBlocks blocks.
// proj decode: projId -> ty = id&1, colHalf = (id>>1)&1, rowTile = id>>2.
// Only colHalf==1 (rb) blocks run the attn tail; tr3 stores exp(tr*sharp).
struct ProjArgs {
  const float* x[2];
  const ushort* Wb[2];
  const float* bl[2];
  const float* br[2];
  ushort* lb[2];
  ushort* rb[2];
  int N[2];
  // fused attn entries, indexed e = ty*2 + colHalf (only e=1,3 used)
  const ushort* aW[4];
  const float* ab[4];
  const float* q0[4];   // cols 0..31
  const float* q1[4];   // cols 32..63 (BN=64 entries)
  float* o0[4];
  float* o1[4];
  int BN[4];
  const float* sharp;   // [3]
  // fused hist3
  const int* e0;
  const int* e1;
  const int* e2;
  int* deg;
  int* rank;
  int E;
  int NGh;
  int projBlocks;
  int totalBlocks;
};
__global__ __launch_bounds__(256) void proj_lr_mfma(ProjArgs g) {
  __shared__ float Asf[2 * 128 * 32];   // 2 x 16 KB fp32; attn tile aliases
  __shared__ ushort Bs[2 * 128 * 32];   // 2 x 8 KB bf16
  const int tid = threadIdx.x;

  // ---- Bresenham role decode: proj blocks spread evenly through grid ----
  const int P = g.projBlocks, T = g.totalBlocks;
  const int bid = blockIdx.x;
  const int pcntLo = (int)(((long long)bid * P) / T);
  const int pcntHi = (int)(((long long)(bid + 1) * P) / T);
  const bool isProj = pcntHi > pcntLo;

  // ---- fused hist3 path (uniform branch; no barriers touched) ----
  if (!isProj) {
    const int E = g.E;
    int e = (bid - pcntLo) * 256 + tid;   // histId = bid - projCountBefore
    if (e < 3 * E) {
      int mp = (e >= 2 * E) ? 2 : ((e >= E) ? 1 : 0);
      int el = e - mp * E;
      const int* ep = (mp == 0) ? g.e0 : (mp == 1) ? g.e1 : g.e2;
      int segb = (mp == 2) ? 2 * g.NGh : mp * g.NGh;
      g.rank[e] = atomicAdd(&g.deg[segb + ep[el]], 1);
    }
    return;
  }

  const int pb = pcntLo;                  // projId
  const int ty = pb & 1;
  const int colHalf = (pb >> 1) & 1;
  const float* xp = g.x[ty];
  const int N = g.N[ty];
  const int lane = tid & 63;
  const int wv = tid >> 6;
  const int wm = wv & 1, wn = wv >> 1;
  const int rowBase = (pb >> 2) * 128;
  const ushort* Wbase = g.Wb[ty] + (size_t)colHalf * 128 * 256;

  floatx4 acc[4][4] = {};

  auto stage = [&](int buf, int k0) {
#pragma unroll
    for (int i = 0; i < 4; ++i) {
      const int G = i * 256 + wv * 64 + lane;       // linear LDS granule
      const int row = G >> 3;
      const int cg = (G & 7) ^ (row & 7);           // preswizzled src chunk
      const int xr = min(rowBase + row, N - 1);
      gload16(xp + (size_t)xr * 256 + k0 + cg * 4, &Asf[buf * 4096 + G * 4]);
    }
#pragma unroll
    for (int i = 0; i < 2; ++i) {
      const int G = i * 256 + wv * 64 + lane;
      const int row = G >> 2;
      const int cg = (G & 3) ^ ((row >> 1) & 3);
      gload16(Wbase + (size_t)row * 256 + k0 + cg * 8, &Bs[buf * 4096 + G * 8]);
    }
  };

  stage(0, 0);
  __syncthreads();

  int t = 0;
  for (int k0 = 0; k0 < 256; k0 += 32) {
    if (k0 < 224) stage(t ^ 1, k0 + 32);
    const float* Ab = &Asf[t * 4096];
    const ushort* Bb = &Bs[t * 4096];
    short8 bf[4];
#pragma unroll
    for (int nt = 0; nt < 4; ++nt) {
      const int row = wn * 64 + nt * 16 + (lane & 15);
      const int c = (lane >> 4) ^ ((row >> 1) & 3);
      bf[nt] = *(const short8*)&Bb[(row * 4 + c) * 8];
    }
#pragma unroll
    for (int mt = 0; mt < 4; ++mt) {
      const int row = wm * 64 + mt * 16 + (lane & 15);
      const int c0 = ((lane >> 4) * 2) ^ (row & 7);
      const int c1 = ((lane >> 4) * 2 + 1) ^ (row & 7);
      float4 f0 = *(const float4*)&Ab[(row * 8 + c0) * 4];
      float4 f1 = *(const float4*)&Ab[(row * 8 + c1) * 4];
      short8 a;
      a[0] = (short)f2b(f0.x); a[1] = (short)f2b(f0.y);
      a[2] = (short)f2b(f0.z); a[3] = (short)f2b(f0.w);
      a[4] = (short)f2b(f1.x); a[5] = (short)f2b(f1.y);
      a[6] = (short)f2b(f1.z); a[7] = (short)f2b(f1.w);
#pragma unroll
      for (int nt = 0; nt < 4; ++nt)
        acc[mt][nt] = __builtin_amdgcn_mfma_f32_16x16x32_bf16(a, bf[nt], acc[mt][nt], 0, 0, 0);
    }
    __syncthreads();
    t ^= 1;
  }

  // ---- C-write to global (+ swizzled LDS tile only when tail needed) ----
  ushort* tile = (ushort*)Asf;   // [row][swizzled chunk] 128x128 bf16
  const float* bias = colHalf ? g.br[ty] : g.bl[ty];
  ushort* outp = colHalf ? g.rb[ty] : g.lb[ty];
#pragma unroll
  for (int mt = 0; mt < 4; ++mt)
#pragma unroll
    for (int nt = 0; nt < 4; ++nt) {
      int col = wn * 64 + nt * 16 + (lane & 15);
      float bv = bias[col];
#pragma unroll
      for (int vi = 0; vi < 4; ++vi) {
        int row = wm * 64 + mt * 16 + (lane >> 4) * 4 + vi;   // local 0..127
        ushort v = f2b(acc[mt][nt][vi] + bv);
        if (colHalf)
          tile[row * 128 + (((col >> 3) ^ (row & 15)) << 3) + (col & 7)] = v;
        if (rowBase + row < N) outp[(size_t)(rowBase + row) * 128 + col] = v;
      }
    }
  if (colHalf == 0) return;   // tl cancels in softmax: no al tail needed
  __syncthreads();            // tile visible to all waves (uniform branch)

  // ---- attn projection + tanh-dot from LDS tile x global aW ----
  const int e = ty * 2 + colHalf;        // e in {1, 3}
  const int NB = g.BN[e] >> 4;
  const ushort* aW = g.aW[e];
  floatx4 acc2[2][4] = {};
  for (int k0 = 0; k0 < 128; k0 += 32) {
    short8 bf2[4];
#pragma unroll
    for (int nt = 0; nt < 4; ++nt)
      if (nt < NB)
        bf2[nt] = *(const short8*)(aW + (size_t)(nt * 16 + (lane & 15)) * 128 +
                                   k0 + (lane >> 4) * 8);
#pragma unroll
    for (int mt = 0; mt < 2; ++mt) {
      const int row = wv * 32 + mt * 16 + (lane & 15);
      const int c8 = (k0 >> 3) + (lane >> 4);          // chunk 0..15
      short8 a = *(const short8*)&tile[row * 128 + ((c8 ^ (row & 15)) << 3)];
#pragma unroll
      for (int nt = 0; nt < 4; ++nt)
        if (nt < NB)
          acc2[mt][nt] = __builtin_amdgcn_mfma_f32_16x16x32_bf16(a, bf2[nt], acc2[mt][nt], 0, 0, 0);
    }
  }

  const float* ab = g.ab[e];
  const int l15 = lane & 15;
  const bool two = (NB == 4);
  // segment sharpening: e==1 -> gg (sharp[0]); e==3 -> gp (sharp[1]) for o0,
  // pp (sharp[2]) for o1. tr3 stores exp(tr*sharp) directly.
  const float shLo = (e == 1) ? g.sharp[0] : g.sharp[1];
  const float shHi = g.sharp[2];
  float bv2[4];
#pragma unroll
  for (int nt = 0; nt < 4; ++nt) bv2[nt] = (nt < NB) ? ab[nt * 16 + l15] : 0.f;
  float q0v0 = g.q0[e][l15], q0v1 = g.q0[e][16 + l15];
  float q1v0 = 0.f, q1v1 = 0.f;
  if (two) { q1v0 = g.q1[e][l15]; q1v1 = g.q1[e][16 + l15]; }
  float* o0 = g.o0[e];
  float* o1 = g.o1[e];
#pragma unroll
  for (int mt = 0; mt < 2; ++mt)
#pragma unroll
    for (int vi = 0; vi < 4; ++vi) {
      float slo = tanhf(acc2[mt][0][vi] + bv2[0]) * q0v0
                + tanhf(acc2[mt][1][vi] + bv2[1]) * q0v1;
      float shi = 0.f;
      if (two)
        shi = tanhf(acc2[mt][2][vi] + bv2[2]) * q1v0
            + tanhf(acc2[mt][3][vi] + bv2[3]) * q1v1;
#pragma unroll
      for (int m = 8; m >= 1; m >>= 1) {
        slo += __shfl_xor(slo, m, 64);   // xor<16 stays in the 16-lane group
        shi += __shfl_xor(shi, m, 64);
      }
      const int row = rowBase + wv * 32 + mt * 16 + (lane >> 4) * 4 + vi;
      if (l15 == 0 && row < N) {
        o0[row] = expf(slo * shLo);
        if (two) o1[row] = expf(shi * shHi);
      }
    }
}

// ------- hierarchical scan: A) tile scan, B) partials, C) add prefix ------
__global__ __launch_bounds__(256) void scanA_kernel(
    const int* __restrict__ deg, int* __restrict__ offsets,
    int* __restrict__ tile_tot, int n) {
  __shared__ int wtot[4];
  const int t = threadIdx.x;
  const int base = blockIdx.x * 2048 + t * 8;
  int v[8], pre[8], s = 0;
#pragma unroll
  for (int j = 0; j < 8; ++j) {
    v[j] = (base + j < n) ? deg[base + j] : 0;
    pre[j] = s;
    s += v[j];
  }
  const int lane = t & 63, wv = t >> 6;
  int x = s;
#pragma unroll
  for (int o = 1; o < 64; o <<= 1) {
    int u = __shfl_up(x, o, 64);
    if (lane >= o) x += u;
  }
  if (lane == 63) wtot[wv] = x;
  __syncthreads();
  int wpre = 0;
#pragma unroll
  for (int j = 0; j < 4; ++j) wpre += (j < wv) ? wtot[j] : 0;
  int excl = wpre + x - s;
#pragma unroll
  for (int j = 0; j < 8; ++j)
    if (base + j < n) offsets[base + j] = excl + pre[j];
  if (t == 255) tile_tot[blockIdx.x] = wpre + x;
}

__global__ __launch_bounds__(256) void scanB_kernel(
    const int* __restrict__ tile_tot, int* __restrict__ tile_pre,
    int* __restrict__ offsets, int T, int n) {
  __shared__ int wtot[4];
  const int t = threadIdx.x;
  int v = (t < T) ? tile_tot[t] : 0;
  const int lane = t & 63, wv = t >> 6;
  int x = v;
#pragma unroll
  for (int o = 1; o < 64; o <<= 1) {
    int u = __shfl_up(x, o, 64);
    if (lane >= o) x += u;
  }
  if (lane == 63) wtot[wv] = x;
  __syncthreads();
  int wpre = 0;
#pragma unroll
  for (int j = 0; j < 4; ++j) wpre += (j < wv) ? wtot[j] : 0;
  if (t < T) tile_pre[t] = wpre + x - v;
  if (t == 255) offsets[n] = wpre + x;  // grand total
}

__global__ __launch_bounds__(256) void scanC_kernel(
    int* __restrict__ offsets, const int* __restrict__ tile_pre, int n) {
  const int add = tile_pre[blockIdx.x];
  const int base = blockIdx.x * 2048 + threadIdx.x * 8;
#pragma unroll
  for (int j = 0; j < 8; ++j)
    if (base + j < n) offsets[base + j] += add;
}

// ------- scatter3: pos = offsets[node] + rank[e]; writes {d*256, w} -------
// w = etr[tail] (pre-exponentiated in proj's attn tail; tl cancels in the
// per-head softmax so no head term and no expf here).
__global__ __launch_bounds__(256) void scatter3_kernel(
    const int* __restrict__ e0, const int* __restrict__ e1,
    const int* __restrict__ e2, const int* __restrict__ rank,
    const int* __restrict__ offsets,
    const float* __restrict__ etr, int2* __restrict__ recs,
    int E, int NG, int NP) {
  int e = blockIdx.x * 256 + threadIdx.x;
  if (e >= 3 * E) return;
  int mp = (e >= 2 * E) ? 2 : ((e >= E) ? 1 : 0);
  int el = e - mp * E;
  const int* ep = (mp == 0) ? e0 : (mp == 1) ? e1 : e2;
  int s = ep[el], d = ep[el + E];
  int hb = (mp == 2) ? 2 * NG : mp * NG;                 // head/offsets base
  int tb = (mp == 0) ? 0 : (mp == 1) ? NG : NG + NP;     // etr segment base
  float w = etr[tb + d];
  recs[offsets[hb + s] + rank[e]] = make_int2(d << 8, __float_as_int(w));
}

// ------- fused gather + relation combine: QUARTER per OUTPUT node ---------
__global__ __launch_bounds__(256) void gather_combine(
    const ushort* __restrict__ rb_gene, const ushort* __restrict__ rb_prot,
    const ushort* __restrict__ lb_gene, const ushort* __restrict__ lb_prot,
    const int* __restrict__ offsets, const int2* __restrict__ recs,
    const float* __restrict__ cgW, const float* __restrict__ cgb,
    const float* __restrict__ cpW, const float* __restrict__ cpb,
    float* __restrict__ out_gene, float* __restrict__ out_prot,
    int NG, int NP) {
  const int lane = threadIdx.x & 63;
  const int l16 = lane & 15;
  const int node = blockIdx.x * 16 + (threadIdx.x >> 4);
  if (node >= NG + NP) return;
  const bool isGene = node < NG;
  const unsigned coloff = (unsigned)l16 << 4;   // 16 B per lane
  const unsigned OMASK = 0x00FFFF00u;           // bounds stray row offsets

  const int h0 = isGene ? node : NG + node;     // gg for genes / pp for prots
  const int j0a = offsets[h0];
  const int ca = offsets[h0 + 1] - j0a;
  int j0b = 0, cb2 = 0;
  if (isGene) {
    j0b = offsets[NG + node];
    cb2 = offsets[NG + node + 1] - j0b;
  }

  float a0[8] = {0.f, 0.f, 0.f, 0.f, 0.f, 0.f, 0.f, 0.f};
  float a1[8] = {0.f, 0.f, 0.f, 0.f, 0.f, 0.f, 0.f, 0.f};
  float ds0 = 0.f, ds1 = 0.f;
  const ushort* rtA = isGene ? rb_gene : rb_prot;

  if (isGene) {
    const int cmax = (ca > cb2) ? ca : cb2;
    if (cmax > 0) {
      int2 rA[4], rB[4];
#pragma unroll
      for (int p = 0; p < 4; ++p) {
        rA[p] = recs[j0a + ((p < ca) ? p : 0)];
        rB[p] = recs[j0b + ((p < cb2) ? p : 0)];
      }
      const int nit = (cmax + 3) >> 2;
      for (int it = 0; it < nit; ++it) {
        const int b = it * 4;
        float wA[4], wB[4];
        uint4 vA[4], vB[4];
#pragma unroll
        for (int p = 0; p < 4; ++p) {
          wA[p] = (b + p < ca)  ? __int_as_float(rA[p].y) : 0.f;
          wB[p] = (b + p < cb2) ? __int_as_float(rB[p].y) : 0.f;
          vA[p] = *(const uint4*)((const char*)rtA + (((unsigned)rA[p].x & OMASK) + coloff));
          vB[p] = *(const uint4*)((const char*)rb_prot + (((unsigned)rB[p].x & OMASK) + coloff));
        }
        const int nb = b + 4;
#pragma unroll
        for (int p = 0; p < 4; ++p) {
          rA[p] = recs[j0a + ((nb + p < ca) ? nb + p : 0)];
          rB[p] = recs[j0b + ((nb + p < cb2) ? nb + p : 0)];
        }
#pragma unroll
        for (int p = 0; p < 4; ++p) {
          ds0 += wA[p];
          a0[0] += b2f_lo(vA[p].x) * wA[p]; a0[1] += b2f_hi(vA[p].x) * wA[p];
          a0[2] += b2f_lo(vA[p].y) * wA[p]; a0[3] += b2f_hi(vA[p].y) * wA[p];
          a0[4] += b2f_lo(vA[p].z) * wA[p]; a0[5] += b2f_hi(vA[p].z) * wA[p];
          a0[6] += b2f_lo(vA[p].w) * wA[p]; a0[7] += b2f_hi(vA[p].w) * wA[p];
          ds1 += wB[p];
          a1[0] += b2f_lo(vB[p].x) * wB[p]; a1[1] += b2f_hi(vB[p].x) * wB[p];
          a1[2] += b2f_lo(vB[p].y) * wB[p]; a1[3] += b2f_hi(vB[p].y) * wB[p];
          a1[4] += b2f_lo(vB[p].z) * wB[p]; a1[5] += b2f_hi(vB[p].z) * wB[p];
          a1[6] += b2f_lo(vB[p].w) * wB[p]; a1[7] += b2f_hi(vB[p].w) * wB[p];
        }
      }
    }
  } else {
    if (ca > 0) {
      int2 r0 = recs[j0a];
      int2 r1 = recs[j0a + ((1 < ca) ? 1 : 0)];
      int2 r2 = recs[j0a + ((2 < ca) ? 2 : 0)];
      int2 r3 = recs[j0a + ((3 < ca) ? 3 : 0)];
      const int nit = (ca + 3) >> 2;
      for (int it = 0; it < nit; ++it) {
        const int b = it * 4;
        const float w0 = (b < ca)     ? __int_as_float(r0.y) : 0.f;
        const float w1 = (b + 1 < ca) ? __int_as_float(r1.y) : 0.f;
        const float w2 = (b + 2 < ca) ? __int_as_float(r2.y) : 0.f;
        const float w3 = (b + 3 < ca) ? __int_as_float(r3.y) : 0.f;
        const uint4 v0 = *(const uint4*)((const char*)rtA + (((unsigned)r0.x & OMASK) + coloff));
        const uint4 v1 = *(const uint4*)((const char*)rtA + (((unsigned)r1.x & OMASK) + coloff));
        const uint4 v2 = *(const uint4*)((const char*)rtA + (((unsigned)r2.x & OMASK) + coloff));
        const uint4 v3 = *(const uint4*)((const char*)rtA + (((unsigned)r3.x & OMASK) + coloff));
        const int nb = b + 4;
        r0 = recs[j0a + ((nb < ca) ? nb : 0)];
        r1 = recs[j0a + ((nb + 1 < ca) ? nb + 1 : 0)];
        r2 = recs[j0a + ((nb + 2 < ca) ? nb + 2 : 0)];
        r3 = recs[j0a + ((nb + 3 < ca) ? nb + 3 : 0)];
        ds0 += (w0 + w1) + (w2 + w3);
        a0[0] += b2f_lo(v0.x) * w0 + b2f_lo(v1.x) * w1 + b2f_lo(v2.x) * w2 + b2f_lo(v3.x) * w3;
        a0[1] += b2f_hi(v0.x) * w0 + b2f_hi(v1.x) * w1 + b2f_hi(v2.x) * w2 + b2f_hi(v3.x) * w3;
        a0[2] += b2f_lo(v0.y) * w0 + b2f_lo(v1.y) * w1 + b2f_lo(v2.y) * w2 + b2f_lo(v3.y) * w3;
        a0[3] += b2f_hi(v0.y) * w0 + b2f_hi(v1.y) * w1 + b2f_hi(v2.y) * w2 + b2f_hi(v3.y) * w3;
        a0[4] += b2f_lo(v0.z) * w0 + b2f_lo(v1.z) * w1 + b2f_lo(v2.z) * w2 + b2f_lo(v3.z) * w3;
        a0[5] += b2f_hi(v0.z) * w0 + b2f_hi(v1.z) * w1 + b2f_hi(v2.z) * w2 + b2f_hi(v3.z) * w3;
        a0[6] += b2f_lo(v0.w) * w0 + b2f_lo(v1.w) * w1 + b2f_lo(v2.w) * w2 + b2f_lo(v3.w) * w3;
        a0[7] += b2f_hi(v0.w) * w0 + b2f_hi(v1.w) * w1 + b2f_hi(v2.w) * w2 + b2f_hi(v3.w) * w3;
      }
    }
  }

  // ---- epilogue (per quarter; ds is lane-uniform within the quarter) ----
  const float inv0 = 1.f / (ds0 + 1e-16f);
  const float inv1 = 1.f / (ds1 + 1e-16f);
  float g0[8], g1[8], self[8];
#pragma unroll
  for (int c = 0; c < 8; ++c) { g0[c] = a0[c] * inv0; g1[c] = a1[c] * inv1; }
  {
    const ushort* lbp = isGene ? lb_gene + (size_t)node * 128
                               : lb_prot + (size_t)(node - NG) * 128;
    uint4 sv = *(const uint4*)(lbp + l16 * 8);
    self[0] = b2f_lo(sv.x); self[1] = b2f_hi(sv.x);
    self[2] = b2f_lo(sv.y); self[3] = b2f_hi(sv.y);
    self[4] = b2f_lo(sv.z); self[5] = b2f_hi(sv.z);
    self[6] = b2f_lo(sv.w); self[7] = b2f_hi(sv.w);
  }

  const float* cW = isGene ? cgW : cpW;
  const float cb = isGene ? cgb[0] : cpb[0];
  const float4 wlo = *(const float4*)(cW + l16 * 8);
  const float4 whi = *(const float4*)(cW + l16 * 8 + 4);
  float p0 = g0[0] * wlo.x + g0[1] * wlo.y + g0[2] * wlo.z + g0[3] * wlo.w +
             g0[4] * whi.x + g0[5] * whi.y + g0[6] * whi.z + g0[7] * whi.w;
  float p1 = g1[0] * wlo.x + g1[1] * wlo.y + g1[2] * wlo.z + g1[3] * wlo.w +
             g1[4] * whi.x + g1[5] * whi.y + g1[6] * whi.z + g1[7] * whi.w;
  float ps = self[0] * wlo.x + self[1] * wlo.y + self[2] * wlo.z + self[3] * wlo.w +
             self[4] * whi.x + self[5] * whi.y + self[6] * whi.z + self[7] * whi.w;
#pragma unroll
  for (int m = 8; m >= 1; m >>= 1) {  // reduce the quarter's 16 col-lanes
    p0 += __shfl_xor(p0, m, 64);
    p1 += __shfl_xor(p1, m, 64);
    ps += __shfl_xor(ps, m, 64);
  }
  const float s0 = p0 + cb, s1 = p1 + cb, ss = ps + cb;
  const float mx = isGene ? fmaxf(fmaxf(s0, s1), ss) : fmaxf(s0, ss);
  const float e0 = expf(s0 - mx);
  const float e1 = isGene ? expf(s1 - mx) : 0.f;
  const float es = expf(ss - mx);
  const float sum = e0 + e1 + es;
  const float b0 = e0 / sum, b1 = e1 / sum, bs = es / sum;

  float4 o0, o1;
  o0.x = fmaxf(g0[0] * b0 + g1[0] * b1 + self[0] * bs, 0.f);
  o0.y = fmaxf(g0[1] * b0 + g1[1] * b1 + self[1] * bs, 0.f);
  o0.z = fmaxf(g0[2] * b0 + g1[2] * b1 + self[2] * bs, 0.f);
  o0.w = fmaxf(g0[3] * b0 + g1[3] * b1 + self[3] * bs, 0.f);
  o1.x = fmaxf(g0[4] * b0 + g1[4] * b1 + self[4] * bs, 0.f);
  o1.y = fmaxf(g0[5] * b0 + g1[5] * b1 + self[5] * bs, 0.f);
  o1.z = fmaxf(g0[6] * b0 + g1[6] * b1 + self[6] * bs, 0.f);
  o1.w = fmaxf(g0[7] * b0 + g1[7] * b1 + self[7] * bs, 0.f);
  float* op = isGene ? out_gene + (size_t)node * 128
                     : out_prot + (size_t)(node - NG) * 128;
  *(float4*)(op + l16 * 8) = o0;
  *(float4*)(op + l16 * 8 + 4) = o1;
}

// ---------------------------------------------------------------------------
extern "C" void kernel_launch(void* const* d_in, const int* in_sizes, int n_in,
                              void* d_out, int out_size, void* d_ws,
                              size_t ws_size, hipStream_t stream) {
  const float* x_gene  = (const float*)d_in[0];
  const float* x_prot  = (const float*)d_in[1];
  const float* Wl_gene = (const float*)d_in[2];
  const float* bl_gene = (const float*)d_in[3];
  const float* Wr_gene = (const float*)d_in[4];
  const float* br_gene = (const float*)d_in[5];
  const float* Wl_prot = (const float*)d_in[6];
  const float* bl_prot = (const float*)d_in[7];
  const float* Wr_prot = (const float*)d_in[8];
  const float* br_prot = (const float*)d_in[9];
  const float* alW     = (const float*)d_in[10];  // [3,32,128] contiguous
  const float* alb     = (const float*)d_in[11];  // [3,32] contiguous
  const float* arW     = (const float*)d_in[12];
  const float* arb     = (const float*)d_in[13];
  const float* qw      = (const float*)d_in[14];  // [3,64,1]
  const float* sharp   = (const float*)d_in[15];
  const float* cgW     = (const float*)d_in[16];
  const float* cgb     = (const float*)d_in[17];
  const float* cpW     = (const float*)d_in[18];
  const float* cpb     = (const float*)d_in[19];
  const int* e_gg      = (const int*)d_in[20];
  const int* e_gp      = (const int*)d_in[21];
  const int* e_pp      = (const int*)d_in[22];

  const int NG = in_sizes[0] / 256;
  const int NP = in_sizes[1] / 256;
  const int E  = in_sizes[20] / 2;
  const int NPG = (NG + 127) & ~127;
  const int NT = 2 * NG + NP;          // concatenated head-node space
  const int NR = NG + 2 * NP;          // concatenated tail-node space (etr)

  char* base = (char*)d_ws;
  size_t off = 0;
  auto alloc = [&](size_t bytes) {
    void* p = base + off;
    off = (off + bytes + 255) & ~(size_t)255;
    return p;
  };
  ushort* Wlr_gene = (ushort*)alloc(256 * 256 * 2);
  ushort* Wlr_prot = (ushort*)alloc(256 * 256 * 2);
  ushort* alWb     = (ushort*)alloc(96 * 128 * 2);
  ushort* arWb     = (ushort*)alloc(96 * 128 * 2);
  ushort* lb_gene  = (ushort*)alloc((size_t)NPG * 128 * 2);
  ushort* rb_gene  = (ushort*)alloc((size_t)NPG * 128 * 2);
  ushort* lb_prot  = (ushort*)alloc((size_t)NPG * 128 * 2);
  ushort* rb_prot  = (ushort*)alloc((size_t)NPG * 128 * 2);
  int*    deg      = (int*)alloc((size_t)NT * 4);
  int*    offsets  = (int*)alloc((size_t)(NT + 1) * 4);
  const int TILES  = (NT + 2047) / 2048;
  int*    tile_tot = (int*)alloc((size_t)TILES * 4);
  int*    tile_pre = (int*)alloc((size_t)TILES * 4);
  int*    rank     = (int*)alloc((size_t)(3 * E) * 4);
  int2*   recs     = (int2*)alloc((size_t)(3 * E) * sizeof(int2));
  float*  etr      = (float*)alloc((size_t)NR * 4);

  float* out_gene = (float*)d_out;
  float* out_prot = out_gene + (size_t)NG * 128;

  dim3 blk(256);

  // ---- 0) deg memset (must precede fused hist) + weight conversions ----
  hipMemsetAsync(deg, 0, (size_t)NT * sizeof(int), stream);
  {
    CvtArgs a;
    const float* srcs[8] = {Wl_gene, Wr_gene, Wl_prot, Wr_prot, alW, arW,
                            Wl_gene, Wl_gene};
    ushort* dsts[8] = {Wlr_gene, Wlr_gene + 128 * 256,
                       Wlr_prot, Wlr_prot + 128 * 256, alWb, arWb,
                       Wlr_gene, Wlr_gene};
    int sizes[8] = {128 * 256, 128 * 256, 128 * 256, 128 * 256,
                    96 * 128, 96 * 128, 0, 0};
    int b = 0;
    for (int j = 0; j < 8; ++j) {
      a.src[j] = srcs[j]; a.dst[j] = dsts[j];
      a.valid[j] = sizes[j]; a.total[j] = sizes[j];
      a.bstart[j] = b;
      b += (sizes[j] / 4 + 255) / 256;
    }
    a.bstart[8] = b;
    cvt_multi<<<b, blk, 0, stream>>>(a);
  }

  // ---- 1) fused proj + attn + hist, Bresenham-interleaved (1 dispatch) ----
  const int gridE3 = (3 * E + 255) / 256;
  const int projBlocks = (NPG / 128) * 4;
  {
    ProjArgs p;
    p.x[0] = x_gene; p.x[1] = x_prot;
    p.Wb[0] = Wlr_gene; p.Wb[1] = Wlr_prot;
    p.bl[0] = bl_gene; p.bl[1] = bl_prot;
    p.br[0] = br_gene; p.br[1] = br_prot;
    p.lb[0] = lb_gene; p.lb[1] = lb_prot;
    p.rb[0] = rb_gene; p.rb[1] = rb_prot;
    p.N[0] = NG; p.N[1] = NP;
    // attn entries (only e=1,3 reached; e=0,2 filled with safe dupes)
    p.aW[0] = arWb;            p.ab[0] = arb;      p.BN[0] = 32;
    p.q0[0] = qw + 32; p.q1[0] = qw + 32;  p.o0[0] = etr;          p.o1[0] = etr;
    p.aW[1] = arWb;            p.ab[1] = arb;      p.BN[1] = 32;
    p.q0[1] = qw + 32; p.q1[1] = qw + 32;  p.o0[1] = etr;          p.o1[1] = etr;
    p.aW[2] = arWb + 32 * 128; p.ab[2] = arb + 32; p.BN[2] = 64;
    p.q0[2] = qw + 96; p.q1[2] = qw + 160; p.o0[2] = etr + NG;     p.o1[2] = etr + NG + NP;
    p.aW[3] = arWb + 32 * 128; p.ab[3] = arb + 32; p.BN[3] = 64;
    p.q0[3] = qw + 96; p.q1[3] = qw + 160; p.o0[3] = etr + NG;     p.o1[3] = etr + NG + NP;
    p.sharp = sharp;
    // hist
    p.e0 = e_gg; p.e1 = e_gp; p.e2 = e_pp;
    p.deg = deg; p.rank = rank; p.E = E; p.NGh = NG;
    p.projBlocks = projBlocks;
    p.totalBlocks = projBlocks + gridE3;
    proj_lr_mfma<<<projBlocks + gridE3, blk, 0, stream>>>(p);
  }

  // ---- 2) CSR scan + scatter{d*256, etr[tail]} ----
  scanA_kernel<<<TILES, blk, 0, stream>>>(deg, offsets, tile_tot, NT);
  scanB_kernel<<<1, blk, 0, stream>>>(tile_tot, tile_pre, offsets, TILES, NT);
  scanC_kernel<<<TILES, blk, 0, stream>>>(offsets, tile_pre, NT);
  scatter3_kernel<<<gridE3, blk, 0, stream>>>(e_gg, e_gp, e_pp, rank, offsets,
                                              etr, recs, E, NG, NP);

  // ---- 3) fused gather + relation combine (1 dispatch) ----
  gather_combine<<<(NG + NP + 15) / 16, blk, 0, stream>>>(
      rb_gene, rb_prot, lb_gene, lb_prot, offsets, recs,
      cgW, cgb, cpW, cpb, out_gene, out_prot, NG, NP);
}